// Round 1
// baseline (274.301 us; speedup 1.0000x reference)
//
#include <hip/hip_runtime.h>

typedef __bf16 bf16;
typedef __bf16 bf16x8 __attribute__((ext_vector_type(8)));
typedef __bf16 bf16x4 __attribute__((ext_vector_type(4)));
typedef float floatx4 __attribute__((ext_vector_type(4)));

#define HIDDEN 1024
#define SEQ 2048
#define BATCH 4
#define ATT_SCALE 0.0625f
#define LN_EPS 1e-5f

// ---------------- fp32 -> bf16 conversion ----------------
__global__ void cvt_f32_bf16(const float* __restrict__ in, bf16* __restrict__ out, int n4) {
    int i = blockIdx.x * blockDim.x + threadIdx.x;
    if (i >= n4) return;
    float4 v = ((const float4*)in)[i];
    bf16x4 o;
    o[0] = (bf16)v.x; o[1] = (bf16)v.y; o[2] = (bf16)v.z; o[3] = (bf16)v.w;
    ((bf16x4*)out)[i] = o;
}

// ---------------- async global->LDS helper ----------------
__device__ __forceinline__ void gload_lds16(const void* g, void* l) {
    __builtin_amdgcn_global_load_lds(
        (const __attribute__((address_space(1))) unsigned int*)g,
        (__attribute__((address_space(3))) unsigned int*)l, 16, 0, 0);
}

// ---------------- GEMM: C = A (MxK) * B^T (B is NxK), bf16 inputs ----------------
// MODE 0: write bf16 C = acc * scale
// MODE 2: write fp32 C = acc + bias[col] + resid[row*N+col]
#define BM 128
#define BN 128
#define BK 64

template <int MODE>
__global__ __launch_bounds__(256)
void gemm_bt(const bf16* __restrict__ A, const bf16* __restrict__ Bw,
             void* __restrict__ Cout,
             const float* __restrict__ bias, const float* __restrict__ resid,
             int M, int N, int K, float scale,
             long sA, long sB, long sC) {
    __shared__ __attribute__((aligned(16))) bf16 As[BM * BK];
    __shared__ __attribute__((aligned(16))) bf16 Bs[BN * BK];

    const int z = blockIdx.z;
    A += (long)z * sA;
    Bw += (long)z * sB;

    const int t = threadIdx.x;
    const int lane = t & 63;
    const int w = t >> 6;            // wave 0..3
    const int wr = (w >> 1) * 64;    // wave row offset in tile
    const int wc = (w & 1) * 64;     // wave col offset in tile

    const int row0 = blockIdx.y * BM;
    const int col0 = blockIdx.x * BN;

    const int srow = t >> 3;         // 0..31
    const int scol = (t & 7) * 8;    // k-offset within BK

    floatx4 acc[4][4] = {};

    const int nk = K / BK;
    for (int ks = 0; ks < nk; ++ks) {
        const int k0 = ks * BK;
#pragma unroll
        for (int i = 0; i < 4; ++i) {
            gload_lds16(A + (long)(row0 + i * 32 + srow) * K + k0 + scol, &As[i * 2048 + t * 8]);
            gload_lds16(Bw + (long)(col0 + i * 32 + srow) * K + k0 + scol, &Bs[i * 2048 + t * 8]);
        }
        __syncthreads();
#pragma unroll
        for (int kk = 0; kk < 2; ++kk) {
            bf16x8 af[4], bfr[4];
#pragma unroll
            for (int m = 0; m < 4; ++m)
                af[m] = *(const bf16x8*)(&As[(wr + m * 16 + (lane & 15)) * BK + kk * 32 + (lane >> 4) * 8]);
#pragma unroll
            for (int n = 0; n < 4; ++n)
                bfr[n] = *(const bf16x8*)(&Bs[(wc + n * 16 + (lane & 15)) * BK + kk * 32 + (lane >> 4) * 8]);
#pragma unroll
            for (int m = 0; m < 4; ++m)
#pragma unroll
                for (int n = 0; n < 4; ++n)
                    acc[m][n] = __builtin_amdgcn_mfma_f32_16x16x32_bf16(af[m], bfr[n], acc[m][n], 0, 0, 0);
        }
        __syncthreads();
    }

    const int rquad = (lane >> 4) * 4;
    const int cfrag = lane & 15;

    if constexpr (MODE == 0) {
        bf16* C = ((bf16*)Cout) + (long)z * sC;
#pragma unroll
        for (int m = 0; m < 4; ++m) {
#pragma unroll
            for (int i = 0; i < 4; ++i) {
                long gr = row0 + wr + m * 16 + rquad + i;
                bf16* crow = C + gr * N + col0 + wc + cfrag;
#pragma unroll
                for (int n = 0; n < 4; ++n)
                    crow[n * 16] = (bf16)(acc[m][n][i] * scale);
            }
        }
    } else {
        float* C = (float*)Cout;
#pragma unroll
        for (int m = 0; m < 4; ++m) {
#pragma unroll
            for (int i = 0; i < 4; ++i) {
                long gr = row0 + wr + m * 16 + rquad + i;
#pragma unroll
                for (int n = 0; n < 4; ++n) {
                    int gc = col0 + wc + n * 16 + cfrag;
                    C[gr * N + gc] = acc[m][n][i] + bias[gc] + resid[gr * N + gc];
                }
            }
        }
    }
}

// ---------------- transpose per batch: (SEQ x HIDDEN) -> (HIDDEN x SEQ) ----------------
__global__ void transpose_v(const bf16* __restrict__ in, bf16* __restrict__ out) {
    __shared__ __attribute__((aligned(16))) bf16 tile[64][72];
    const int z = blockIdx.z;
    const bf16* ib = in + (long)z * SEQ * HIDDEN;
    bf16* ob = out + (long)z * SEQ * HIDDEN;
    const int d0 = blockIdx.x * 64;  // hidden
    const int s0 = blockIdx.y * 64;  // seq
    const int t = threadIdx.x;
    const int r = t >> 4;
    const int c = (t & 15) * 4;
#pragma unroll
    for (int i = 0; i < 4; ++i) {
        bf16x4 v = *(const bf16x4*)&ib[(long)(s0 + r + i * 16) * HIDDEN + d0 + c];
        *(bf16x4*)&tile[r + i * 16][c] = v;
    }
    __syncthreads();
#pragma unroll
    for (int i = 0; i < 4; ++i) {
        const int dr = r + i * 16;
        bf16x4 o;
#pragma unroll
        for (int j = 0; j < 4; ++j) o[j] = tile[c + j][dr];
        *(bf16x4*)&ob[(long)(d0 + dr) * SEQ + s0 + c] = o;
    }
}

// ---------------- row softmax, in-place on bf16 scores ----------------
__global__ void softmax_rows(bf16* __restrict__ S, const int* __restrict__ mask) {
    const int b = blockIdx.y;
    const int row = blockIdx.x;
    bf16* srow = S + ((long)b * SEQ + row) * SEQ;
    const int* mrow = mask + b * SEQ;
    const int t = threadIdx.x;

    bf16x8 sv = *(const bf16x8*)&srow[t * 8];
    int4 m0 = ((const int4*)mrow)[t * 2];
    int4 m1 = ((const int4*)mrow)[t * 2 + 1];
    int mk[8] = {m0.x, m0.y, m0.z, m0.w, m1.x, m1.y, m1.z, m1.w};

    float v[8];
    float mx = -1e30f;
#pragma unroll
    for (int j = 0; j < 8; ++j) {
        float s = (float)sv[j];
        if (mk[j] == 0) s = -1e9f;
        v[j] = s;
        mx = fmaxf(mx, s);
    }
    __shared__ float redm[4], reds[4];
#pragma unroll
    for (int off = 32; off > 0; off >>= 1) mx = fmaxf(mx, __shfl_down(mx, off));
    if ((t & 63) == 0) redm[t >> 6] = mx;
    __syncthreads();
    mx = fmaxf(fmaxf(redm[0], redm[1]), fmaxf(redm[2], redm[3]));

    float sum = 0.f;
#pragma unroll
    for (int j = 0; j < 8; ++j) {
        v[j] = __expf(v[j] - mx);
        sum += v[j];
    }
#pragma unroll
    for (int off = 32; off > 0; off >>= 1) sum += __shfl_down(sum, off);
    if ((t & 63) == 0) reds[t >> 6] = sum;
    __syncthreads();
    sum = reds[0] + reds[1] + reds[2] + reds[3];
    float inv = 1.0f / sum;

    bf16x8 o;
#pragma unroll
    for (int j = 0; j < 8; ++j) o[j] = (bf16)(v[j] * inv);
    *(bf16x8*)&srow[t * 8] = o;
}

// ---------------- LayerNorm: h (fp32) -> out (fp32) ----------------
__global__ void layernorm_out(const float* __restrict__ h, const float* __restrict__ gamma,
                              const float* __restrict__ beta, float* __restrict__ out) {
    const long row = blockIdx.x;
    const float* hr = h + row * HIDDEN;
    const int t = threadIdx.x;
    float4 v = ((const float4*)hr)[t];
    float s = v.x + v.y + v.z + v.w;
    float sq = v.x * v.x + v.y * v.y + v.z * v.z + v.w * v.w;
    __shared__ float rs[4], rq[4];
#pragma unroll
    for (int off = 32; off > 0; off >>= 1) {
        s += __shfl_down(s, off);
        sq += __shfl_down(sq, off);
    }
    if ((t & 63) == 0) { rs[t >> 6] = s; rq[t >> 6] = sq; }
    __syncthreads();
    s = rs[0] + rs[1] + rs[2] + rs[3];
    sq = rq[0] + rq[1] + rq[2] + rq[3];
    float mu = s * (1.0f / HIDDEN);
    float var = sq * (1.0f / HIDDEN) - mu * mu;
    float rinv = rsqrtf(var + LN_EPS);
    float4 g = ((const float4*)gamma)[t];
    float4 bt = ((const float4*)beta)[t];
    float4 o;
    o.x = (v.x - mu) * rinv * g.x + bt.x;
    o.y = (v.y - mu) * rinv * g.y + bt.y;
    o.z = (v.z - mu) * rinv * g.z + bt.z;
    o.w = (v.w - mu) * rinv * g.w + bt.w;
    ((float4*)(out + row * HIDDEN))[t] = o;
}

// ---------------- launch ----------------
extern "C" void kernel_launch(void* const* d_in, const int* in_sizes, int n_in,
                              void* d_out, int out_size, void* d_ws, size_t ws_size,
                              hipStream_t stream) {
    const float* x     = (const float*)d_in[0];
    const int*   mask  = (const int*)d_in[1];
    const float* Wq    = (const float*)d_in[2];
    const float* Wk    = (const float*)d_in[3];
    const float* Wv    = (const float*)d_in[4];
    const float* Wo    = (const float*)d_in[5];
    const float* bo    = (const float*)d_in[6];
    const float* gamma = (const float*)d_in[7];
    const float* beta  = (const float*)d_in[8];
    float* out = (float*)d_out;

    char* ws = (char*)d_ws;
    const long MB = 1024L * 1024L;
    bf16* xb = (bf16*)(ws + 0 * MB);    // 16 MB
    bf16* wq = (bf16*)(ws + 16 * MB);   // 2 MB
    bf16* wk = (bf16*)(ws + 18 * MB);
    bf16* wv = (bf16*)(ws + 20 * MB);
    bf16* wo = (bf16*)(ws + 22 * MB);
    bf16* q  = (bf16*)(ws + 24 * MB);   // 16 MB
    bf16* k  = (bf16*)(ws + 40 * MB);   // 16 MB
    bf16* v  = (bf16*)(ws + 56 * MB);   // 16 MB
    bf16* vt = (bf16*)(ws + 72 * MB);   // 16 MB
    bf16* S  = (bf16*)(ws + 88 * MB);   // 32 MB (scores, then probs in-place)
    bf16* ctx = v;                      // reuse: v dead after transpose
    float* h = (float*)(ws + 24 * MB);  // 32 MB, reuse q/k region (dead after scores)

    const int BS = BATCH * SEQ;         // 8192 rows
    dim3 blk(256);

    // conversions
    {
        int n4 = BS * HIDDEN / 4;
        cvt_f32_bf16<<<dim3((n4 + 255) / 256), blk, 0, stream>>>(x, xb, n4);
        int w4 = HIDDEN * HIDDEN / 4;
        cvt_f32_bf16<<<dim3((w4 + 255) / 256), blk, 0, stream>>>(Wq, wq, w4);
        cvt_f32_bf16<<<dim3((w4 + 255) / 256), blk, 0, stream>>>(Wk, wk, w4);
        cvt_f32_bf16<<<dim3((w4 + 255) / 256), blk, 0, stream>>>(Wv, wv, w4);
        cvt_f32_bf16<<<dim3((w4 + 255) / 256), blk, 0, stream>>>(Wo, wo, w4);
    }

    // QKV projections: (8192x1024) * (1024x1024)^T
    gemm_bt<0><<<dim3(HIDDEN / BN, BS / BM, 1), blk, 0, stream>>>(
        xb, wq, q, nullptr, nullptr, BS, HIDDEN, HIDDEN, 1.0f, 0, 0, 0);
    gemm_bt<0><<<dim3(HIDDEN / BN, BS / BM, 1), blk, 0, stream>>>(
        xb, wk, k, nullptr, nullptr, BS, HIDDEN, HIDDEN, 1.0f, 0, 0, 0);
    gemm_bt<0><<<dim3(HIDDEN / BN, BS / BM, 1), blk, 0, stream>>>(
        xb, wv, v, nullptr, nullptr, BS, HIDDEN, HIDDEN, 1.0f, 0, 0, 0);

    // V -> V^T per batch
    transpose_v<<<dim3(HIDDEN / 64, SEQ / 64, BATCH), blk, 0, stream>>>(v, vt);

    // scores: per batch (2048x2048) = q * k^T * SCALE
    gemm_bt<0><<<dim3(SEQ / BN, SEQ / BM, BATCH), blk, 0, stream>>>(
        q, k, S, nullptr, nullptr, SEQ, SEQ, HIDDEN, ATT_SCALE,
        (long)SEQ * HIDDEN, (long)SEQ * HIDDEN, (long)SEQ * SEQ);

    // softmax rows in-place
    softmax_rows<<<dim3(SEQ, BATCH), blk, 0, stream>>>(S, mask);

    // ctx: per batch (2048x1024) = P * Vt^T
    gemm_bt<0><<<dim3(HIDDEN / BN, SEQ / BM, BATCH), blk, 0, stream>>>(
        S, vt, ctx, nullptr, nullptr, SEQ, HIDDEN, SEQ, 1.0f,
        (long)SEQ * SEQ, (long)HIDDEN * SEQ, (long)SEQ * HIDDEN);

    // out projection + bias + residual -> h (fp32)
    gemm_bt<2><<<dim3(HIDDEN / BN, BS / BM, 1), blk, 0, stream>>>(
        ctx, wo, h, bo, x, BS, HIDDEN, HIDDEN, 1.0f, 0, 0, 0);

    // LayerNorm -> out
    layernorm_out<<<dim3(BS), blk, 0, stream>>>(h, gamma, beta, out);
}

// Round 2
// 250.971 us; speedup vs baseline: 1.0930x; 1.0930x over previous
//
#include <hip/hip_runtime.h>

typedef __bf16 bf16;
typedef __bf16 bf16x8 __attribute__((ext_vector_type(8)));
typedef __bf16 bf16x4 __attribute__((ext_vector_type(4)));
typedef float floatx4 __attribute__((ext_vector_type(4)));

#define HIDDEN 1024
#define SEQ 2048
#define BATCH 4
#define ATT_SCALE 0.0625f
#define LN_EPS 1e-5f

__device__ __forceinline__ void gload_lds16(const void* g, void* l) {
    __builtin_amdgcn_global_load_lds(
        (const __attribute__((address_space(1))) unsigned int*)g,
        (__attribute__((address_space(3))) unsigned int*)l, 16, 0, 0);
}

#define GBAR() asm volatile("s_barrier" ::: "memory")
#define MFMA(a, b, c) __builtin_amdgcn_mfma_f32_16x16x32_bf16(a, b, c, 0, 0, 0)

// ---------------- fp32 -> bf16 conversion ----------------
__global__ void cvt_f32_bf16(const float* __restrict__ in, bf16* __restrict__ out, int n4) {
    int i = blockIdx.x * blockDim.x + threadIdx.x;
    if (i >= n4) return;
    float4 v = ((const float4*)in)[i];
    bf16x4 o;
    o[0] = (bf16)v.x; o[1] = (bf16)v.y; o[2] = (bf16)v.z; o[3] = (bf16)v.w;
    ((bf16x4*)out)[i] = o;
}

// fused weight conversion: Wq,Wk,Wv -> wqkv (3072x1024 rows concat), Wo -> wo
__global__ void cvt_weights(const float* __restrict__ Wq, const float* __restrict__ Wk,
                            const float* __restrict__ Wv, const float* __restrict__ Wo,
                            bf16* __restrict__ wqkv, bf16* __restrict__ wo) {
    const int NW = HIDDEN * HIDDEN / 4;  // float4 groups per matrix
    int i = blockIdx.x * blockDim.x + threadIdx.x;
    const float* src; bf16* dst; int j;
    if (i < NW)            { src = Wq; dst = wqkv;                     j = i; }
    else if (i < 2 * NW)   { src = Wk; dst = wqkv + HIDDEN * HIDDEN;   j = i - NW; }
    else if (i < 3 * NW)   { src = Wv; dst = wqkv + 2 * HIDDEN * HIDDEN; j = i - 2 * NW; }
    else                   { src = Wo; dst = wo;                       j = i - 3 * NW; }
    float4 v = ((const float4*)src)[j];
    bf16x4 o;
    o[0] = (bf16)v.x; o[1] = (bf16)v.y; o[2] = (bf16)v.z; o[3] = (bf16)v.w;
    ((bf16x4*)dst)[j] = o;
}

// ---------------- GEMM: C = A (MxK) * B^T (B is NxK), bf16 inputs ----------------
// 256x128 tile, BK=64, 512 threads (8 waves, 2Mx4N), 3-buffer LDS pipeline,
// 4 phases per K-tile, counted vmcnt, st_16x32 swizzle both-sides.
// MODE 0: bf16 C = acc * scale ; MODE 2: fp32 C = acc + bias[col] + resid[row,col]
template <int MODE>
__global__ __launch_bounds__(512, 2)
void gemm_bt256(const bf16* __restrict__ A, const bf16* __restrict__ Bw,
                void* __restrict__ Cout,
                const float* __restrict__ bias, const float* __restrict__ resid,
                int lda, int ldb, int ldc, int K, float scale,
                long sA, long sB, long sC) {
    __shared__ __attribute__((aligned(16))) char lds[147456];  // 3 x (32KB A + 16KB B)

    const int z = blockIdx.z;
    const char* Ab = (const char*)(A + (long)z * sA);
    const char* Bb = (const char*)(Bw + (long)z * sB);

    const int t = threadIdx.x;
    const int lane = t & 63;
    const int w = t >> 6;
    const int wm = w >> 2;     // 0..1 -> rows wm*128
    const int wn = w & 3;      // 0..3 -> cols wn*32
    const int l15 = lane & 15;
    const int l4 = lane >> 4;

    const int row0 = blockIdx.y * 256;
    const int col0 = blockIdx.x * 128;

    // pre-swizzled global staging sources (inverse st_16x32 of linear LDS dest)
    const char* asrc[4];
    const char* bsrc[2];
#pragma unroll
    for (int u = 0; u < 4; ++u) {
        int d = u * 8192 + t * 16;
        int p = d ^ (((d >> 9) & 1) << 5);
        asrc[u] = Ab + (long)(row0 + (p >> 7)) * (lda * 2L) + (p & 127);
    }
#pragma unroll
    for (int u = 0; u < 2; ++u) {
        int d = u * 8192 + t * 16;
        int p = d ^ (((d >> 9) & 1) << 5);
        bsrc[u] = Bb + (long)(col0 + (p >> 7)) * (ldb * 2L) + (p & 127);
    }
    const int ldst = t * 16;

    floatx4 acc[8][2] = {};
    const int nk = K / 64;

    // prologue: stage tile0 -> buf0, tile1 -> buf1
#pragma unroll
    for (int u = 0; u < 4; ++u) gload_lds16(asrc[u], &lds[u * 8192 + ldst]);
#pragma unroll
    for (int u = 0; u < 2; ++u) gload_lds16(bsrc[u], &lds[32768 + u * 8192 + ldst]);
#pragma unroll
    for (int u = 0; u < 4; ++u) gload_lds16(asrc[u] + 128, &lds[49152 + u * 8192 + ldst]);
#pragma unroll
    for (int u = 0; u < 2; ++u) gload_lds16(bsrc[u] + 128, &lds[49152 + 32768 + u * 8192 + ldst]);
    asm volatile("s_waitcnt vmcnt(6)" ::: "memory");
    GBAR();

    int cb = 0;  // current LDS buffer byte base
    for (int tile = 0; tile < nk; ++tile) {
        int nb = cb + 98304; if (nb >= 147456) nb -= 147456;  // buffer for tile+2
        const long kb = (long)(tile + 2) * 128;
        const bool pf = (tile + 2) < nk;

        auto rdA = [&](int m, int kk) {
            int off = (wm * 128 + m * 16 + l15) * 128 + kk * 64 + l4 * 16;
            off ^= ((off >> 9) & 1) << 5;
            return *(const bf16x8*)&lds[cb + off];
        };
        auto rdB = [&](int n, int kk) {
            int off = (wn * 32 + n * 16 + l15) * 128 + kk * 64 + l4 * 16;
            off ^= ((off >> 9) & 1) << 5;
            return *(const bf16x8*)&lds[cb + 32768 + off];
        };

        bf16x8 af[4], bfr[2];

        // ---- phase 1: m0-3 x n0-1, kk=0; stage A units 0,1 of tile+2
#pragma unroll
        for (int m = 0; m < 4; ++m) af[m] = rdA(m, 0);
#pragma unroll
        for (int n = 0; n < 2; ++n) bfr[n] = rdB(n, 0);
        if (pf) {
            gload_lds16(asrc[0] + kb, &lds[nb + 0 * 8192 + ldst]);
            gload_lds16(asrc[1] + kb, &lds[nb + 1 * 8192 + ldst]);
        }
        GBAR();
        __builtin_amdgcn_s_setprio(1);
#pragma unroll
        for (int m = 0; m < 4; ++m)
#pragma unroll
            for (int n = 0; n < 2; ++n) acc[m][n] = MFMA(af[m], bfr[n], acc[m][n]);
        __builtin_amdgcn_s_setprio(0);
        GBAR();

        // ---- phase 2: m4-7 x n0-1, kk=0 (reuse B frags); stage A units 2,3
#pragma unroll
        for (int m = 0; m < 4; ++m) af[m] = rdA(4 + m, 0);
        if (pf) {
            gload_lds16(asrc[2] + kb, &lds[nb + 2 * 8192 + ldst]);
            gload_lds16(asrc[3] + kb, &lds[nb + 3 * 8192 + ldst]);
        }
        GBAR();
        __builtin_amdgcn_s_setprio(1);
#pragma unroll
        for (int m = 0; m < 4; ++m)
#pragma unroll
            for (int n = 0; n < 2; ++n) acc[4 + m][n] = MFMA(af[m], bfr[n], acc[4 + m][n]);
        __builtin_amdgcn_s_setprio(0);
        GBAR();

        // ---- phase 3: m0-3, kk=1 (new B frags); stage B units 0,1
#pragma unroll
        for (int m = 0; m < 4; ++m) af[m] = rdA(m, 1);
#pragma unroll
        for (int n = 0; n < 2; ++n) bfr[n] = rdB(n, 1);
        if (pf) {
            gload_lds16(bsrc[0] + kb, &lds[nb + 32768 + 0 * 8192 + ldst]);
            gload_lds16(bsrc[1] + kb, &lds[nb + 32768 + 1 * 8192 + ldst]);
        }
        GBAR();
        __builtin_amdgcn_s_setprio(1);
#pragma unroll
        for (int m = 0; m < 4; ++m)
#pragma unroll
            for (int n = 0; n < 2; ++n) acc[m][n] = MFMA(af[m], bfr[n], acc[m][n]);
        __builtin_amdgcn_s_setprio(0);
        GBAR();

        // ---- phase 4: m4-7, kk=1; counted wait + buffer rotate
#pragma unroll
        for (int m = 0; m < 4; ++m) af[m] = rdA(4 + m, 1);
        GBAR();
        __builtin_amdgcn_s_setprio(1);
#pragma unroll
        for (int m = 0; m < 4; ++m)
#pragma unroll
            for (int n = 0; n < 2; ++n) acc[4 + m][n] = MFMA(af[m], bfr[n], acc[4 + m][n]);
        __builtin_amdgcn_s_setprio(0);
        if (pf) asm volatile("s_waitcnt vmcnt(6)" ::: "memory");
        else    asm volatile("s_waitcnt vmcnt(0)" ::: "memory");
        GBAR();

        cb += 49152; if (cb == 147456) cb = 0;
    }

    // ---- epilogue
    const int rq = l4 * 4;
    if constexpr (MODE == 0) {
        bf16* C = ((bf16*)Cout) + (long)z * sC;
#pragma unroll
        for (int m = 0; m < 8; ++m)
#pragma unroll
            for (int i = 0; i < 4; ++i) {
                long gr = row0 + wm * 128 + m * 16 + rq + i;
#pragma unroll
                for (int n = 0; n < 2; ++n) {
                    int gc = col0 + wn * 32 + n * 16 + l15;
                    C[gr * ldc + gc] = (bf16)(acc[m][n][i] * scale);
                }
            }
    } else {
        float* C = (float*)Cout;
#pragma unroll
        for (int m = 0; m < 8; ++m)
#pragma unroll
            for (int i = 0; i < 4; ++i) {
                long gr = row0 + wm * 128 + m * 16 + rq + i;
#pragma unroll
                for (int n = 0; n < 2; ++n) {
                    int gc = col0 + wn * 32 + n * 16 + l15;
                    C[gr * ldc + gc] = acc[m][n][i] + bias[gc] + resid[gr * ldc + gc];
                }
            }
    }
}

// ---------------- transpose V (from fused qkv): per batch (SEQ x 1024 @ld 3072) -> (1024 x SEQ) ----------------
__global__ void transpose_v(const bf16* __restrict__ qkv, bf16* __restrict__ out) {
    __shared__ __attribute__((aligned(16))) bf16 tile[64][72];
    const int z = blockIdx.z;
    const bf16* ib = qkv + (long)z * SEQ * 3072 + 2048;
    bf16* ob = out + (long)z * SEQ * HIDDEN;
    const int d0 = blockIdx.x * 64;  // hidden
    const int s0 = blockIdx.y * 64;  // seq
    const int t = threadIdx.x;
    const int r = t >> 4;
    const int c = (t & 15) * 4;
#pragma unroll
    for (int i = 0; i < 4; ++i) {
        bf16x4 v = *(const bf16x4*)&ib[(long)(s0 + r + i * 16) * 3072 + d0 + c];
        *(bf16x4*)&tile[r + i * 16][c] = v;
    }
    __syncthreads();
#pragma unroll
    for (int i = 0; i < 4; ++i) {
        const int dr = r + i * 16;
        bf16x4 o;
#pragma unroll
        for (int j = 0; j < 4; ++j) o[j] = tile[c + j][dr];
        *(bf16x4*)&ob[(long)(d0 + dr) * SEQ + s0 + c] = o;
    }
}

// ---------------- row softmax, in-place on bf16 scores ----------------
__global__ void softmax_rows(bf16* __restrict__ S, const int* __restrict__ mask) {
    const int b = blockIdx.y;
    const int row = blockIdx.x;
    bf16* srow = S + ((long)b * SEQ + row) * SEQ;
    const int* mrow = mask + b * SEQ;
    const int t = threadIdx.x;

    bf16x8 sv = *(const bf16x8*)&srow[t * 8];
    int4 m0 = ((const int4*)mrow)[t * 2];
    int4 m1 = ((const int4*)mrow)[t * 2 + 1];
    int mk[8] = {m0.x, m0.y, m0.z, m0.w, m1.x, m1.y, m1.z, m1.w};

    float v[8];
    float mx = -1e30f;
#pragma unroll
    for (int j = 0; j < 8; ++j) {
        float s = (float)sv[j];
        if (mk[j] == 0) s = -1e9f;
        v[j] = s;
        mx = fmaxf(mx, s);
    }
    __shared__ float redm[4], reds[4];
#pragma unroll
    for (int off = 32; off > 0; off >>= 1) mx = fmaxf(mx, __shfl_down(mx, off));
    if ((t & 63) == 0) redm[t >> 6] = mx;
    __syncthreads();
    mx = fmaxf(fmaxf(redm[0], redm[1]), fmaxf(redm[2], redm[3]));

    float sum = 0.f;
#pragma unroll
    for (int j = 0; j < 8; ++j) {
        v[j] = __expf(v[j] - mx);
        sum += v[j];
    }
#pragma unroll
    for (int off = 32; off > 0; off >>= 1) sum += __shfl_down(sum, off);
    if ((t & 63) == 0) reds[t >> 6] = sum;
    __syncthreads();
    sum = reds[0] + reds[1] + reds[2] + reds[3];
    float inv = 1.0f / sum;

    bf16x8 o;
#pragma unroll
    for (int j = 0; j < 8; ++j) o[j] = (bf16)(v[j] * inv);
    *(bf16x8*)&srow[t * 8] = o;
}

// ---------------- LayerNorm: h (fp32) -> out (fp32) ----------------
__global__ void layernorm_out(const float* __restrict__ h, const float* __restrict__ gamma,
                              const float* __restrict__ beta, float* __restrict__ out) {
    const long row = blockIdx.x;
    const float* hr = h + row * HIDDEN;
    const int t = threadIdx.x;
    float4 v = ((const float4*)hr)[t];
    float s = v.x + v.y + v.z + v.w;
    float sq = v.x * v.x + v.y * v.y + v.z * v.z + v.w * v.w;
    __shared__ float rs[4], rq[4];
#pragma unroll
    for (int off = 32; off > 0; off >>= 1) {
        s += __shfl_down(s, off);
        sq += __shfl_down(sq, off);
    }
    if ((t & 63) == 0) { rs[t >> 6] = s; rq[t >> 6] = sq; }
    __syncthreads();
    s = rs[0] + rs[1] + rs[2] + rs[3];
    sq = rq[0] + rq[1] + rq[2] + rq[3];
    float mu = s * (1.0f / HIDDEN);
    float var = sq * (1.0f / HIDDEN) - mu * mu;
    float rinv = rsqrtf(var + LN_EPS);
    float4 g = ((const float4*)gamma)[t];
    float4 bt = ((const float4*)beta)[t];
    float4 o;
    o.x = (v.x - mu) * rinv * g.x + bt.x;
    o.y = (v.y - mu) * rinv * g.y + bt.y;
    o.z = (v.z - mu) * rinv * g.z + bt.z;
    o.w = (v.w - mu) * rinv * g.w + bt.w;
    ((float4*)(out + row * HIDDEN))[t] = o;
}

// ---------------- launch ----------------
extern "C" void kernel_launch(void* const* d_in, const int* in_sizes, int n_in,
                              void* d_out, int out_size, void* d_ws, size_t ws_size,
                              hipStream_t stream) {
    const float* x     = (const float*)d_in[0];
    const int*   mask  = (const int*)d_in[1];
    const float* Wq    = (const float*)d_in[2];
    const float* Wk    = (const float*)d_in[3];
    const float* Wv    = (const float*)d_in[4];
    const float* Wo    = (const float*)d_in[5];
    const float* bo    = (const float*)d_in[6];
    const float* gamma = (const float*)d_in[7];
    const float* beta  = (const float*)d_in[8];
    float* out = (float*)d_out;

    char* ws = (char*)d_ws;
    const long MB = 1024L * 1024L;
    bf16* xb   = (bf16*)(ws + 0 * MB);    // 16 MB (x in bf16); reused as ctx later
    bf16* wqkv = (bf16*)(ws + 16 * MB);   // 6 MB (3072x1024)
    bf16* wo   = (bf16*)(ws + 22 * MB);   // 2 MB
    bf16* qkv  = (bf16*)(ws + 24 * MB);   // 48 MB (8192 x 3072)
    bf16* vt   = (bf16*)(ws + 72 * MB);   // 16 MB (per batch 1024 x 2048)
    bf16* S    = (bf16*)(ws + 88 * MB);   // 32 MB scores/probs
    bf16* ctx  = xb;                      // 16 MB, xb dead after QKV GEMM
    float* h   = (float*)(ws + 88 * MB);  // 32 MB, S dead after PV GEMM

    const int BS = BATCH * SEQ;  // 8192
    dim3 blk256(256), blk512(512);

    // conversions
    cvt_f32_bf16<<<dim3(BS * HIDDEN / 4 / 256), blk256, 0, stream>>>(x, xb, BS * HIDDEN / 4);
    cvt_weights<<<dim3(4 * HIDDEN * HIDDEN / 4 / 256), blk256, 0, stream>>>(Wq, Wk, Wv, Wo, wqkv, wo);

    // fused QKV projection: (8192x1024) * (3072x1024)^T -> qkv (ld 3072)
    gemm_bt256<0><<<dim3(3072 / 128, BS / 256, 1), blk512, 0, stream>>>(
        xb, wqkv, qkv, nullptr, nullptr, HIDDEN, HIDDEN, 3072, HIDDEN, 1.0f, 0, 0, 0);

    // V -> V^T per batch (v = qkv cols 2048..3071)
    transpose_v<<<dim3(HIDDEN / 64, SEQ / 64, BATCH), blk256, 0, stream>>>(qkv, vt);

    // scores: per batch (2048x2048) = q * k^T * SCALE   (q,k inside qkv, ld 3072)
    gemm_bt256<0><<<dim3(SEQ / 128, SEQ / 256, BATCH), blk512, 0, stream>>>(
        qkv, qkv + 1024, S, nullptr, nullptr, 3072, 3072, SEQ, HIDDEN, ATT_SCALE,
        (long)SEQ * 3072, (long)SEQ * 3072, (long)SEQ * SEQ);

    // softmax rows in-place
    softmax_rows<<<dim3(SEQ, BATCH), blk256, 0, stream>>>(S, mask);

    // ctx: per batch (2048x1024) = P * Vt^T
    gemm_bt256<0><<<dim3(HIDDEN / 128, SEQ / 256, BATCH), blk512, 0, stream>>>(
        S, vt, ctx, nullptr, nullptr, SEQ, SEQ, HIDDEN, SEQ, 1.0f,
        (long)SEQ * SEQ, (long)HIDDEN * SEQ, (long)SEQ * HIDDEN);

    // out projection + bias + residual -> h (fp32)
    gemm_bt256<2><<<dim3(HIDDEN / 128, BS / 256, 1), blk512, 0, stream>>>(
        ctx, wo, h, bo, x, HIDDEN, HIDDEN, HIDDEN, HIDDEN, 1.0f, 0, 0, 0);

    // LayerNorm -> out
    layernorm_out<<<dim3(BS), blk256, 0, stream>>>(h, gamma, beta, out);
}

// Round 3
// 225.056 us; speedup vs baseline: 1.2188x; 1.1152x over previous
//
#include <hip/hip_runtime.h>

typedef __bf16 bf16;
typedef __bf16 bf16x8 __attribute__((ext_vector_type(8)));
typedef __bf16 bf16x4 __attribute__((ext_vector_type(4)));
typedef float floatx4 __attribute__((ext_vector_type(4)));

#define HIDDEN 1024
#define SEQ 2048
#define BATCH 4
#define ATT_SCALE 0.0625f
#define LN_EPS 1e-5f

__device__ __forceinline__ void gload_lds16(const void* g, void* l) {
    __builtin_amdgcn_global_load_lds(
        (const __attribute__((address_space(1))) unsigned int*)g,
        (__attribute__((address_space(3))) unsigned int*)l, 16, 0, 0);
}

#define GBAR() asm volatile("s_barrier" ::: "memory")
#define MFMA(a, b, c) __builtin_amdgcn_mfma_f32_16x16x32_bf16(a, b, c, 0, 0, 0)

// ---------------- fp32 -> bf16 conversion ----------------
__global__ void cvt_f32_bf16(const float* __restrict__ in, bf16* __restrict__ out, int n4) {
    int i = blockIdx.x * blockDim.x + threadIdx.x;
    if (i >= n4) return;
    float4 v = ((const float4*)in)[i];
    bf16x4 o;
    o[0] = (bf16)v.x; o[1] = (bf16)v.y; o[2] = (bf16)v.z; o[3] = (bf16)v.w;
    ((bf16x4*)out)[i] = o;
}

// fused weight conversion: Wq,Wk,Wv -> wqkv (3072x1024 rows concat), Wo -> wo
__global__ void cvt_weights(const float* __restrict__ Wq, const float* __restrict__ Wk,
                            const float* __restrict__ Wv, const float* __restrict__ Wo,
                            bf16* __restrict__ wqkv, bf16* __restrict__ wo) {
    const int NW = HIDDEN * HIDDEN / 4;
    int i = blockIdx.x * blockDim.x + threadIdx.x;
    const float* src; bf16* dst; int j;
    if (i < NW)            { src = Wq; dst = wqkv;                       j = i; }
    else if (i < 2 * NW)   { src = Wk; dst = wqkv + HIDDEN * HIDDEN;     j = i - NW; }
    else if (i < 3 * NW)   { src = Wv; dst = wqkv + 2 * HIDDEN * HIDDEN; j = i - 2 * NW; }
    else                   { src = Wo; dst = wo;                         j = i - 3 * NW; }
    float4 v = ((const float4*)src)[j];
    bf16x4 o;
    o[0] = (bf16)v.x; o[1] = (bf16)v.y; o[2] = (bf16)v.z; o[3] = (bf16)v.w;
    ((bf16x4*)dst)[j] = o;
}

// ---------------- GEMM: C = A (MxK) * B^T (B is NxK), bf16 inputs ----------------
// BM=256, BN=NREP*64, BK=64 split in 2 K-phases of 32. 512 threads = 8 waves (2Mx4N).
// LDS: 4-slot ring of kk-halves (A 256x32 + B BNx32, 64B rows -> conflict-free b128 reads).
// Stage-ahead 3 phases, uniform counted vmcnt(2L). Out-of-range stages clamp (write dead slots).
// MODE 0: bf16 C = acc*scale ; MODE 2: fp32 C = acc + bias[col] + resid[row,col]
template <int NREP, int MODE>
__global__ __launch_bounds__(512, 1)
void gemm_p(const bf16* __restrict__ A, const bf16* __restrict__ Bw,
            void* __restrict__ Cout,
            const float* __restrict__ bias, const float* __restrict__ resid,
            int lda, int ldb, int ldc, int K, float scale,
            long sA, long sB, long sC) {
    constexpr int BN = NREP * 64;
    constexpr int ABYTES = 256 * 64;      // 16 KB per A kk-half
    constexpr int BBYTES = BN * 64;       // 16/8 KB per B kk-half
    constexpr int SLOT = ABYTES + BBYTES;
    constexpr int LB = BN / 128;          // B loads per thread per phase (2 or 1)
    constexpr int L = 2 + LB;             // total loads per phase
    constexpr int VW = 2 * L;             // steady-state vmcnt

    __shared__ __attribute__((aligned(16))) char lds[4 * SLOT];

    const int z = blockIdx.z;
    const char* Ab = (const char*)(A + (long)z * sA);
    const char* Bb = (const char*)(Bw + (long)z * sB);
    const long lda2 = lda * 2L, ldb2 = ldb * 2L;

    const int t = threadIdx.x;
    const int lane = t & 63;
    const int w = t >> 6;
    const int wm = w >> 2;        // 0..1
    const int wn = w & 3;         // 0..3
    const int l15 = lane & 15;
    const int l4 = lane >> 4;

    const int row0 = blockIdx.y * 256;
    const int col0 = blockIdx.x * BN;

    // staging sources: within a kk-half, thread t covers bytes p=u*8192+t*16,
    // row = p>>6 (64B rows), byte-in-row = p&63
    const char* aS[2];
#pragma unroll
    for (int u = 0; u < 2; ++u) {
        int p = u * 8192 + t * 16;
        aS[u] = Ab + (long)(row0 + (p >> 6)) * lda2 + (p & 63);
    }
    const char* bS[2];
#pragma unroll
    for (int u = 0; u < LB; ++u) {
        int p = u * 8192 + t * 16;
        bS[u] = Bb + (long)(col0 + (p >> 6)) * ldb2 + (p & 63);
    }
    const int ld16 = t * 16;
    const int nk = K / 64;

    auto STAGE = [&](int slot, int tk, int kk) {
        long off = (long)tk * 128 + kk * 64;
        char* base = &lds[slot * SLOT];
#pragma unroll
        for (int u = 0; u < 2; ++u)
            gload_lds16(aS[u] + off, base + u * 8192 + ld16);
#pragma unroll
        for (int u = 0; u < LB; ++u)
            gload_lds16(bS[u] + off, base + ABYTES + u * 8192 + ld16);
    };

    floatx4 acc[8][NREP] = {};

    // prologue: slot0=(t0,kk0) slot1=(t0,kk1) slot2=(t1,kk0)
    STAGE(0, 0, 0);
    STAGE(1, 0, 1);
    STAGE(2, (1 < nk ? 1 : 0), 0);
    asm volatile("s_waitcnt vmcnt(%0)" :: "n"(VW) : "memory");
    GBAR();

    int cs = 0;  // slot of current tile's kk0
    for (int tile = 0; tile < nk; ++tile) {
#pragma unroll
        for (int ph = 0; ph < 2; ++ph) {
            const char* sb = &lds[((cs + ph) & 3) * SLOT];
            bf16x8 af[8], bfr[NREP];
#pragma unroll
            for (int m = 0; m < 8; ++m)
                af[m] = *(const bf16x8*)(sb + (wm * 128 + m * 16 + l15) * 64 + l4 * 16);
#pragma unroll
            for (int n = 0; n < NREP; ++n)
                bfr[n] = *(const bf16x8*)(sb + ABYTES + (wn * NREP * 16 + n * 16 + l15) * 64 + l4 * 16);

            // stage-ahead: ph0 -> (tile+1, kk1) into slot cs+3 ; ph1 -> (tile+2, kk0) into slot cs
            if (ph == 0) {
                int ts = (tile + 1 < nk) ? tile + 1 : nk - 1;
                STAGE((cs + 3) & 3, ts, 1);
            } else {
                int ts = (tile + 2 < nk) ? tile + 2 : nk - 1;
                STAGE(cs, ts, 0);
            }

            __builtin_amdgcn_s_setprio(1);
#pragma unroll
            for (int m = 0; m < 8; ++m)
#pragma unroll
                for (int n = 0; n < NREP; ++n)
                    acc[m][n] = MFMA(af[m], bfr[n], acc[m][n]);
            __builtin_amdgcn_s_setprio(0);

            asm volatile("s_waitcnt lgkmcnt(0)" ::: "memory");
            asm volatile("s_waitcnt vmcnt(%0)" :: "n"(VW) : "memory");
            GBAR();
        }
        cs = (cs + 2) & 3;
    }

    // ---- epilogue
    const int rq = l4 * 4;
    if constexpr (MODE == 0) {
        bf16* C = ((bf16*)Cout) + (long)z * sC;
#pragma unroll
        for (int m = 0; m < 8; ++m)
#pragma unroll
            for (int i = 0; i < 4; ++i) {
                long gr = row0 + wm * 128 + m * 16 + rq + i;
#pragma unroll
                for (int n = 0; n < NREP; ++n) {
                    int gc = col0 + wn * NREP * 16 + n * 16 + l15;
                    C[gr * ldc + gc] = (bf16)(acc[m][n][i] * scale);
                }
            }
    } else {
        float* C = (float*)Cout;
#pragma unroll
        for (int m = 0; m < 8; ++m)
#pragma unroll
            for (int i = 0; i < 4; ++i) {
                long gr = row0 + wm * 128 + m * 16 + rq + i;
#pragma unroll
                for (int n = 0; n < NREP; ++n) {
                    int gc = col0 + wn * NREP * 16 + n * 16 + l15;
                    C[gr * ldc + gc] = acc[m][n][i] + bias[gc] + resid[gr * ldc + gc];
                }
            }
    }
}

// ---------------- transpose V (from fused qkv): per batch (SEQ x 1024 @ld 3072) -> (1024 x SEQ) ----------------
__global__ void transpose_v(const bf16* __restrict__ qkv, bf16* __restrict__ out) {
    __shared__ __attribute__((aligned(16))) bf16 tile[64][72];
    const int z = blockIdx.z;
    const bf16* ib = qkv + (long)z * SEQ * 3072 + 2048;
    bf16* ob = out + (long)z * SEQ * HIDDEN;
    const int d0 = blockIdx.x * 64;
    const int s0 = blockIdx.y * 64;
    const int t = threadIdx.x;
    const int r = t >> 4;
    const int c = (t & 15) * 4;
#pragma unroll
    for (int i = 0; i < 4; ++i) {
        bf16x4 v = *(const bf16x4*)&ib[(long)(s0 + r + i * 16) * 3072 + d0 + c];
        *(bf16x4*)&tile[r + i * 16][c] = v;
    }
    __syncthreads();
#pragma unroll
    for (int i = 0; i < 4; ++i) {
        const int dr = r + i * 16;
        bf16x4 o;
#pragma unroll
        for (int j = 0; j < 4; ++j) o[j] = tile[c + j][dr];
        *(bf16x4*)&ob[(long)(d0 + dr) * SEQ + s0 + c] = o;
    }
}

// ---------------- row softmax, in-place on bf16 scores ----------------
__global__ void softmax_rows(bf16* __restrict__ S, const int* __restrict__ mask) {
    const int b = blockIdx.y;
    const int row = blockIdx.x;
    bf16* srow = S + ((long)b * SEQ + row) * SEQ;
    const int* mrow = mask + b * SEQ;
    const int t = threadIdx.x;

    bf16x8 sv = *(const bf16x8*)&srow[t * 8];
    int4 m0 = ((const int4*)mrow)[t * 2];
    int4 m1 = ((const int4*)mrow)[t * 2 + 1];
    int mk[8] = {m0.x, m0.y, m0.z, m0.w, m1.x, m1.y, m1.z, m1.w};

    float v[8];
    float mx = -1e30f;
#pragma unroll
    for (int j = 0; j < 8; ++j) {
        float s = (float)sv[j];
        if (mk[j] == 0) s = -1e9f;
        v[j] = s;
        mx = fmaxf(mx, s);
    }
    __shared__ float redm[4], reds[4];
#pragma unroll
    for (int off = 32; off > 0; off >>= 1) mx = fmaxf(mx, __shfl_down(mx, off));
    if ((t & 63) == 0) redm[t >> 6] = mx;
    __syncthreads();
    mx = fmaxf(fmaxf(redm[0], redm[1]), fmaxf(redm[2], redm[3]));

    float sum = 0.f;
#pragma unroll
    for (int j = 0; j < 8; ++j) {
        v[j] = __expf(v[j] - mx);
        sum += v[j];
    }
#pragma unroll
    for (int off = 32; off > 0; off >>= 1) sum += __shfl_down(sum, off);
    if ((t & 63) == 0) reds[t >> 6] = sum;
    __syncthreads();
    sum = reds[0] + reds[1] + reds[2] + reds[3];
    float inv = 1.0f / sum;

    bf16x8 o;
#pragma unroll
    for (int j = 0; j < 8; ++j) o[j] = (bf16)(v[j] * inv);
    *(bf16x8*)&srow[t * 8] = o;
}

// ---------------- LayerNorm: h (fp32) -> out (fp32) ----------------
__global__ void layernorm_out(const float* __restrict__ h, const float* __restrict__ gamma,
                              const float* __restrict__ beta, float* __restrict__ out) {
    const long row = blockIdx.x;
    const float* hr = h + row * HIDDEN;
    const int t = threadIdx.x;
    float4 v = ((const float4*)hr)[t];
    float s = v.x + v.y + v.z + v.w;
    float sq = v.x * v.x + v.y * v.y + v.z * v.z + v.w * v.w;
    __shared__ float rs[4], rq[4];
#pragma unroll
    for (int off = 32; off > 0; off >>= 1) {
        s += __shfl_down(s, off);
        sq += __shfl_down(sq, off);
    }
    if ((t & 63) == 0) { rs[t >> 6] = s; rq[t >> 6] = sq; }
    __syncthreads();
    s = rs[0] + rs[1] + rs[2] + rs[3];
    sq = rq[0] + rq[1] + rq[2] + rq[3];
    float mu = s * (1.0f / HIDDEN);
    float var = sq * (1.0f / HIDDEN) - mu * mu;
    float rinv = rsqrtf(var + LN_EPS);
    float4 g = ((const float4*)gamma)[t];
    float4 bt = ((const float4*)beta)[t];
    float4 o;
    o.x = (v.x - mu) * rinv * g.x + bt.x;
    o.y = (v.y - mu) * rinv * g.y + bt.y;
    o.z = (v.z - mu) * rinv * g.z + bt.z;
    o.w = (v.w - mu) * rinv * g.w + bt.w;
    ((float4*)(out + row * HIDDEN))[t] = o;
}

// ---------------- launch ----------------
extern "C" void kernel_launch(void* const* d_in, const int* in_sizes, int n_in,
                              void* d_out, int out_size, void* d_ws, size_t ws_size,
                              hipStream_t stream) {
    const float* x     = (const float*)d_in[0];
    const int*   mask  = (const int*)d_in[1];
    const float* Wq    = (const float*)d_in[2];
    const float* Wk    = (const float*)d_in[3];
    const float* Wv    = (const float*)d_in[4];
    const float* Wo    = (const float*)d_in[5];
    const float* bo    = (const float*)d_in[6];
    const float* gamma = (const float*)d_in[7];
    const float* beta  = (const float*)d_in[8];
    float* out = (float*)d_out;

    char* ws = (char*)d_ws;
    const long MB = 1024L * 1024L;
    bf16* xb   = (bf16*)(ws + 0 * MB);    // 16 MB; reused as ctx later
    bf16* wqkv = (bf16*)(ws + 16 * MB);   // 6 MB
    bf16* wo   = (bf16*)(ws + 22 * MB);   // 2 MB
    bf16* qkv  = (bf16*)(ws + 24 * MB);   // 48 MB (8192 x 3072)
    bf16* vt   = (bf16*)(ws + 72 * MB);   // 16 MB
    bf16* S    = (bf16*)(ws + 88 * MB);   // 32 MB
    bf16* ctx  = xb;
    float* h   = (float*)(ws + 88 * MB);  // reuse S region

    const int BS = BATCH * SEQ;  // 8192
    dim3 blk256(256), blk512(512);

    cvt_f32_bf16<<<dim3(BS * HIDDEN / 4 / 256), blk256, 0, stream>>>(x, xb, BS * HIDDEN / 4);
    cvt_weights<<<dim3(4 * HIDDEN * HIDDEN / 4 / 256), blk256, 0, stream>>>(Wq, Wk, Wv, Wo, wqkv, wo);

    // fused QKV projection: (8192x1024) * (3072x1024)^T ; NREP2 -> 24x32 = 768 WGs
    gemm_p<2, 0><<<dim3(3072 / 128, BS / 256, 1), blk512, 0, stream>>>(
        xb, wqkv, qkv, nullptr, nullptr, HIDDEN, HIDDEN, 3072, HIDDEN, 1.0f, 0, 0, 0);

    transpose_v<<<dim3(HIDDEN / 64, SEQ / 64, BATCH), blk256, 0, stream>>>(qkv, vt);

    // scores: per batch (2048x2048) = q*k^T*SCALE ; NREP4 -> 8x8x4 = 256 WGs
    gemm_p<4, 0><<<dim3(SEQ / 256, SEQ / 256, BATCH), blk512, 0, stream>>>(
        qkv, qkv + 1024, S, nullptr, nullptr, 3072, 3072, SEQ, HIDDEN, ATT_SCALE,
        (long)SEQ * 3072, (long)SEQ * 3072, (long)SEQ * SEQ);

    softmax_rows<<<dim3(SEQ, BATCH), blk256, 0, stream>>>(S, mask);

    // ctx: per batch (2048x1024) = P * Vt^T ; NREP2 -> 8x8x4 = 256 WGs
    gemm_p<2, 0><<<dim3(HIDDEN / 128, SEQ / 256, BATCH), blk512, 0, stream>>>(
        S, vt, ctx, nullptr, nullptr, SEQ, SEQ, HIDDEN, SEQ, 1.0f,
        (long)SEQ * SEQ, (long)HIDDEN * SEQ, (long)SEQ * HIDDEN);

    // out projection + bias + residual -> h ; NREP2 -> 8x32 = 256 WGs
    gemm_p<2, 2><<<dim3(HIDDEN / 128, BS / 256, 1), blk512, 0, stream>>>(
        ctx, wo, h, bo, x, HIDDEN, HIDDEN, HIDDEN, HIDDEN, 1.0f, 0, 0, 0);

    layernorm_out<<<dim3(BS), blk256, 0, stream>>>(h, gamma, beta, out);
}

// Round 4
// 211.638 us; speedup vs baseline: 1.2961x; 1.0634x over previous
//
#include <hip/hip_runtime.h>

typedef __bf16 bf16;
typedef __bf16 bf16x8 __attribute__((ext_vector_type(8)));
typedef __bf16 bf16x4 __attribute__((ext_vector_type(4)));
typedef float floatx4 __attribute__((ext_vector_type(4)));

#define HIDDEN 1024
#define SEQ 2048
#define BATCH 4
#define ATT_SCALE 0.0625f
#define LN_EPS 1e-5f

__device__ __forceinline__ void gload_lds16(const void* g, void* l) {
    __builtin_amdgcn_global_load_lds(
        (const __attribute__((address_space(1))) unsigned int*)g,
        (__attribute__((address_space(3))) unsigned int*)l, 16, 0, 0);
}

#define GBAR() asm volatile("s_barrier" ::: "memory")
#define MFMA(a, b, c) __builtin_amdgcn_mfma_f32_16x16x32_bf16(a, b, c, 0, 0, 0)

// ---------------- fp32 -> bf16 conversion ----------------
__global__ void cvt_f32_bf16(const float* __restrict__ in, bf16* __restrict__ out, int n4) {
    int i = blockIdx.x * blockDim.x + threadIdx.x;
    if (i >= n4) return;
    float4 v = ((const float4*)in)[i];
    bf16x4 o;
    o[0] = (bf16)v.x; o[1] = (bf16)v.y; o[2] = (bf16)v.z; o[3] = (bf16)v.w;
    ((bf16x4*)out)[i] = o;
}

// Wq,Wk -> wqkv rows 0..2047 ; Wo -> wo
__global__ void cvt_weights(const float* __restrict__ Wq, const float* __restrict__ Wk,
                            const float* __restrict__ Wo,
                            bf16* __restrict__ wqkv, bf16* __restrict__ wo) {
    const int NW = HIDDEN * HIDDEN / 4;
    int i = blockIdx.x * blockDim.x + threadIdx.x;
    const float* src; bf16* dst; int j;
    if (i < NW)          { src = Wq; dst = wqkv;                   j = i; }
    else if (i < 2 * NW) { src = Wk; dst = wqkv + HIDDEN * HIDDEN; j = i - NW; }
    else                 { src = Wo; dst = wo;                     j = i - 2 * NW; }
    float4 v = ((const float4*)src)[j];
    bf16x4 o;
    o[0] = (bf16)v.x; o[1] = (bf16)v.y; o[2] = (bf16)v.z; o[3] = (bf16)v.w;
    ((bf16x4*)dst)[j] = o;
}

// Wv (1024x1024 fp32) -> wvT (1024x1024 bf16, transposed)
__global__ void transpose_w(const float* __restrict__ in, bf16* __restrict__ out) {
    __shared__ __attribute__((aligned(16))) bf16 tile[64][72];
    const int d0 = blockIdx.x * 64;   // input col
    const int f0 = blockIdx.y * 64;   // input row
    const int t = threadIdx.x;
    const int r = t >> 4;
    const int c = (t & 15) * 4;
#pragma unroll
    for (int i = 0; i < 4; ++i) {
        float4 v = *(const float4*)&in[(long)(f0 + r + i * 16) * HIDDEN + d0 + c];
        bf16x4 b;
        b[0] = (bf16)v.x; b[1] = (bf16)v.y; b[2] = (bf16)v.z; b[3] = (bf16)v.w;
        *(bf16x4*)&tile[r + i * 16][c] = b;
    }
    __syncthreads();
#pragma unroll
    for (int i = 0; i < 4; ++i) {
        const int dr = r + i * 16;
        bf16x4 o;
#pragma unroll
        for (int j = 0; j < 4; ++j) o[j] = tile[c + j][dr];
        *(bf16x4*)&out[(long)(d0 + dr) * HIDDEN + f0 + c] = o;
    }
}

// ---------------- GEMM: C = A (MxK) * B^T (B is NxK), bf16 inputs ----------------
// BM=256 fixed. Waves: 2M x WNC N. Wave tile 128 x (NREP*16). BN = WNC*NREP*16.
// 3-slot LDS ring of kk-halves (BK=32 each). 64B rows with 16B-chunk rotation
// ((row>>1)&3) -> conflict-free ds_read_b128; global_load_lds dest linear,
// source carries inverse chunk permutation (both-sides rule).
// MODE 0: bf16 C = acc*scale ; MODE 2: fp32 C = acc + bias[col] + resid (z-offset)
template <int WNC, int NREP, int MODE>
__global__ __launch_bounds__(WNC * 128, 2)
void gemm_p(const bf16* A, const bf16* Bw, void* __restrict__ Cout,
            const float* __restrict__ bias, const float* __restrict__ resid,
            int lda, int ldb, int ldc, int K, float scale,
            long sA, long sB, long sC) {
    constexpr int THREADS = WNC * 128;
    constexpr int BN = WNC * NREP * 16;
    constexpr int ABY = 16384;          // A kk-half bytes (256 rows x 32k x 2B)
    constexpr int BBY = BN * 64;
    constexpr int SLOT = ABY + BBY;
    constexpr int T16 = THREADS * 16;
    constexpr int NU = SLOT / T16;      // loads per thread per slot
    constexpr int AU = ABY / T16;

    __shared__ __attribute__((aligned(16))) char lds[3 * SLOT];

    // XCD-aware block swizzle (nb % 8 == 0 for all launches)
    const int gx = gridDim.x;
    const int nb = gx * gridDim.y;
    const int bid = blockIdx.y * gx + blockIdx.x;
    const int cpx = nb >> 3;
    const int sbid = (bid & 7) * cpx + (bid >> 3);
    const int bx = sbid % gx, by = sbid / gx;

    const int z = blockIdx.z;
    const char* Ab = (const char*)(A + (long)z * sA);
    const char* Bb = (const char*)(Bw + (long)z * sB);
    const long lda2 = lda * 2L, ldb2 = ldb * 2L;

    const int t = threadIdx.x;
    const int lane = t & 63;
    const int w = t >> 6;
    const int wm = (WNC == 4) ? (w >> 2) : (w >> 1);
    const int wn = (WNC == 4) ? (w & 3) : (w & 1);
    const int l15 = lane & 15;
    const int l4 = lane >> 4;

    const int row0 = by * 256;
    const int col0 = bx * BN;

    // staging sources with inverse chunk rotation
    const char* srcs[NU];
#pragma unroll
    for (int u = 0; u < NU; ++u) {
        int pl = u * T16 + t * 16;
        if (u < AU) {
            int lrow = pl >> 6;
            int c = (((pl >> 4) & 3) - ((lrow >> 1) & 3)) & 3;
            srcs[u] = Ab + (long)(row0 + lrow) * lda2 + c * 16;
        } else {
            int pb = pl - ABY;
            int lrow = pb >> 6;
            int c = (((pb >> 4) & 3) - ((lrow >> 1) & 3)) & 3;
            srcs[u] = Bb + (long)(col0 + lrow) * ldb2 + c * 16;
        }
    }
    const int ld16 = t * 16;

    auto STAGE = [&](int slot, long koff) {
        char* base = &lds[slot * SLOT];
#pragma unroll
        for (int u = 0; u < NU; ++u)
            gload_lds16(srcs[u] + koff, base + u * T16 + ld16);
    };

    floatx4 acc[8][NREP] = {};
    const int nk = K / 64, np = 2 * nk;

    STAGE(0, 0);    // phase 0: tile0 kk0
    STAGE(1, 64);   // phase 1: tile0 kk1
    asm volatile("s_waitcnt vmcnt(%0)" :: "n"(NU) : "memory");
    GBAR();

    int slot = 0;
    for (int pp = 0; pp < np; ++pp) {
        const char* sb = &lds[slot * SLOT];
        bf16x8 af[8], bfr[NREP];
#pragma unroll
        for (int m = 0; m < 8; ++m) {
            int lr = wm * 128 + m * 16 + l15;
            int p = (l4 + ((lr >> 1) & 3)) & 3;
            af[m] = *(const bf16x8*)(sb + lr * 64 + p * 16);
        }
#pragma unroll
        for (int n = 0; n < NREP; ++n) {
            int lr = wn * NREP * 16 + n * 16 + l15;
            int p = (l4 + ((lr >> 1) & 3)) & 3;
            bfr[n] = *(const bf16x8*)(sb + ABY + lr * 64 + p * 16);
        }

        const int pf = pp + 2;
        int s2 = slot + 2; if (s2 >= 3) s2 -= 3;
        if (pf < np) STAGE(s2, (long)(pf >> 1) * 128 + (long)(pf & 1) * 64);

        __builtin_amdgcn_s_setprio(1);
#pragma unroll
        for (int m = 0; m < 8; ++m)
#pragma unroll
            for (int n = 0; n < NREP; ++n)
                acc[m][n] = MFMA(af[m], bfr[n], acc[m][n]);
        __builtin_amdgcn_s_setprio(0);

        asm volatile("s_waitcnt lgkmcnt(0)" ::: "memory");
        if (pf < np) asm volatile("s_waitcnt vmcnt(%0)" :: "n"(NU) : "memory");
        else         asm volatile("s_waitcnt vmcnt(0)" ::: "memory");
        GBAR();
        slot = (slot == 2) ? 0 : slot + 1;
    }

    // ---- epilogue
    const int rq = l4 * 4;
    if constexpr (MODE == 0) {
        bf16* C = ((bf16*)Cout) + (long)z * sC;
#pragma unroll
        for (int m = 0; m < 8; ++m)
#pragma unroll
            for (int i = 0; i < 4; ++i) {
                long gr = row0 + wm * 128 + m * 16 + rq + i;
#pragma unroll
                for (int n = 0; n < NREP; ++n) {
                    int gc = col0 + wn * NREP * 16 + n * 16 + l15;
                    C[gr * ldc + gc] = (bf16)(acc[m][n][i] * scale);
                }
            }
    } else {
        float* C = (float*)Cout + (long)z * sC;
        const float* R = resid + (long)z * sC;
#pragma unroll
        for (int m = 0; m < 8; ++m)
#pragma unroll
            for (int i = 0; i < 4; ++i) {
                long gr = row0 + wm * 128 + m * 16 + rq + i;
#pragma unroll
                for (int n = 0; n < NREP; ++n) {
                    int gc = col0 + wn * NREP * 16 + n * 16 + l15;
                    C[gr * ldc + gc] = acc[m][n][i] + bias[gc] + R[gr * ldc + gc];
                }
            }
    }
}

// ---------------- transpose VWc (from fused qkv): per batch (SEQ x 1024 @ld 3072) -> (1024 x SEQ) ----------------
__global__ void transpose_v(const bf16* __restrict__ qkv, bf16* __restrict__ out) {
    __shared__ __attribute__((aligned(16))) bf16 tile[64][72];
    const int z = blockIdx.z;
    const bf16* ib = qkv + (long)z * SEQ * 3072 + 2048;
    bf16* ob = out + (long)z * SEQ * HIDDEN;
    const int d0 = blockIdx.x * 64;
    const int s0 = blockIdx.y * 64;
    const int t = threadIdx.x;
    const int r = t >> 4;
    const int c = (t & 15) * 4;
#pragma unroll
    for (int i = 0; i < 4; ++i) {
        bf16x4 v = *(const bf16x4*)&ib[(long)(s0 + r + i * 16) * 3072 + d0 + c];
        *(bf16x4*)&tile[r + i * 16][c] = v;
    }
    __syncthreads();
#pragma unroll
    for (int i = 0; i < 4; ++i) {
        const int dr = r + i * 16;
        bf16x4 o;
#pragma unroll
        for (int j = 0; j < 4; ++j) o[j] = tile[c + j][dr];
        *(bf16x4*)&ob[(long)(d0 + dr) * SEQ + s0 + c] = o;
    }
}

// ---------------- row softmax, in-place on bf16 scores ----------------
__global__ void softmax_rows(bf16* __restrict__ S, const int* __restrict__ mask) {
    const int b = blockIdx.y;
    const int row = blockIdx.x;
    bf16* srow = S + ((long)b * SEQ + row) * SEQ;
    const int* mrow = mask + b * SEQ;
    const int t = threadIdx.x;

    bf16x8 sv = *(const bf16x8*)&srow[t * 8];
    int4 m0 = ((const int4*)mrow)[t * 2];
    int4 m1 = ((const int4*)mrow)[t * 2 + 1];
    int mk[8] = {m0.x, m0.y, m0.z, m0.w, m1.x, m1.y, m1.z, m1.w};

    float v[8];
    float mx = -1e30f;
#pragma unroll
    for (int j = 0; j < 8; ++j) {
        float s = (float)sv[j];
        if (mk[j] == 0) s = -1e9f;
        v[j] = s;
        mx = fmaxf(mx, s);
    }
    __shared__ float redm[4], reds[4];
#pragma unroll
    for (int off = 32; off > 0; off >>= 1) mx = fmaxf(mx, __shfl_down(mx, off));
    if ((t & 63) == 0) redm[t >> 6] = mx;
    __syncthreads();
    mx = fmaxf(fmaxf(redm[0], redm[1]), fmaxf(redm[2], redm[3]));

    float sum = 0.f;
#pragma unroll
    for (int j = 0; j < 8; ++j) {
        v[j] = __expf(v[j] - mx);
        sum += v[j];
    }
#pragma unroll
    for (int off = 32; off > 0; off >>= 1) sum += __shfl_down(sum, off);
    if ((t & 63) == 0) reds[t >> 6] = sum;
    __syncthreads();
    sum = reds[0] + reds[1] + reds[2] + reds[3];
    float inv = 1.0f / sum;

    bf16x8 o;
#pragma unroll
    for (int j = 0; j < 8; ++j) o[j] = (bf16)(v[j] * inv);
    *(bf16x8*)&srow[t * 8] = o;
}

// ---------------- LayerNorm: h (fp32) -> out (fp32) ----------------
__global__ void layernorm_out(const float* __restrict__ h, const float* __restrict__ gamma,
                              const float* __restrict__ beta, float* __restrict__ out) {
    const long row = blockIdx.x;
    const float* hr = h + row * HIDDEN;
    const int t = threadIdx.x;
    float4 v = ((const float4*)hr)[t];
    float s = v.x + v.y + v.z + v.w;
    float sq = v.x * v.x + v.y * v.y + v.z * v.z + v.w * v.w;
    __shared__ float rs[4], rq[4];
#pragma unroll
    for (int off = 32; off > 0; off >>= 1) {
        s += __shfl_down(s, off);
        sq += __shfl_down(sq, off);
    }
    if ((t & 63) == 0) { rs[t >> 6] = s; rq[t >> 6] = sq; }
    __syncthreads();
    s = rs[0] + rs[1] + rs[2] + rs[3];
    sq = rq[0] + rq[1] + rq[2] + rq[3];
    float mu = s * (1.0f / HIDDEN);
    float var = sq * (1.0f / HIDDEN) - mu * mu;
    float rinv = rsqrtf(var + LN_EPS);
    float4 g = ((const float4*)gamma)[t];
    float4 bt = ((const float4*)beta)[t];
    float4 o;
    o.x = (v.x - mu) * rinv * g.x + bt.x;
    o.y = (v.y - mu) * rinv * g.y + bt.y;
    o.z = (v.z - mu) * rinv * g.z + bt.z;
    o.w = (v.w - mu) * rinv * g.w + bt.w;
    ((float4*)(out + row * HIDDEN))[t] = o;
}

// ---------------- launch ----------------
extern "C" void kernel_launch(void* const* d_in, const int* in_sizes, int n_in,
                              void* d_out, int out_size, void* d_ws, size_t ws_size,
                              hipStream_t stream) {
    const float* x     = (const float*)d_in[0];
    const int*   mask  = (const int*)d_in[1];
    const float* Wq    = (const float*)d_in[2];
    const float* Wk    = (const float*)d_in[3];
    const float* Wv    = (const float*)d_in[4];
    const float* Wo    = (const float*)d_in[5];
    const float* bo    = (const float*)d_in[6];
    const float* gamma = (const float*)d_in[7];
    const float* beta  = (const float*)d_in[8];
    float* out = (float*)d_out;

    char* ws = (char*)d_ws;
    const long MB = 1024L * 1024L;
    bf16* qkv  = (bf16*)(ws + 0 * MB);    // 48 MB (8192 x 3072) [Q|K|VWc]
    bf16* xb   = (bf16*)(ws + 48 * MB);   // 16 MB; vt reuses after QKV
    bf16* vt   = (bf16*)(ws + 48 * MB);   // 16 MB (per batch 1024 x 2048)
    bf16* wqkv = (bf16*)(ws + 64 * MB);   // 6 MB (3072 x 1024): Wq,Wk,Wc
    bf16* wo   = (bf16*)(ws + 70 * MB);   // 2 MB
    bf16* wvT  = (bf16*)(ws + 72 * MB);   // 2 MB
    bf16* S    = (bf16*)(ws + 74 * MB);   // 32 MB scores/probs
    float* h   = (float*)(ws + 0 * MB);   // 32 MB over qkv (dead after scores+transpose)

    const int BS = BATCH * SEQ;  // 8192
    dim3 blk256(256), blk512(512);

    cvt_f32_bf16<<<dim3(BS * HIDDEN / 4 / 256), blk256, 0, stream>>>(x, xb, BS * HIDDEN / 4);
    cvt_weights<<<dim3(3 * HIDDEN * HIDDEN / 4 / 256), blk256, 0, stream>>>(Wq, Wk, Wo, wqkv, wo);
    transpose_w<<<dim3(16, 16), blk256, 0, stream>>>(Wv, wvT);

    // Wc = Wo * Wv : (1024x1024)*(1024x1024)^T-form with B=Wv^T -> wqkv rows 2048..3071
    gemm_p<2, 4, 0><<<dim3(1024 / 128, 1024 / 256, 1), blk256, 0, stream>>>(
        wo, wvT, wqkv + 2048 * HIDDEN, nullptr, nullptr,
        HIDDEN, HIDDEN, HIDDEN, HIDDEN, 1.0f, 0, 0, 0);

    // fused QKV+Wc projection: (8192x1024)*(3072x1024)^T -> [Q|K|VWc]
    gemm_p<4, 4, 0><<<dim3(3072 / 256, BS / 256, 1), blk512, 0, stream>>>(
        xb, wqkv, qkv, nullptr, nullptr, HIDDEN, HIDDEN, 3072, HIDDEN, 1.0f, 0, 0, 0);

    // VWc -> vt per batch
    transpose_v<<<dim3(HIDDEN / 64, SEQ / 64, BATCH), blk256, 0, stream>>>(qkv, vt);

    // scores: per batch (2048x2048) = q*k^T*SCALE
    gemm_p<4, 4, 0><<<dim3(SEQ / 256, SEQ / 256, BATCH), blk512, 0, stream>>>(
        qkv, qkv + 1024, S, nullptr, nullptr, 3072, 3072, SEQ, HIDDEN, ATT_SCALE,
        (long)SEQ * 3072, (long)SEQ * 3072, (long)SEQ * SEQ);

    softmax_rows<<<dim3(SEQ, BATCH), blk256, 0, stream>>>(S, mask);

    // h = P * vt^T + bo + x : per batch (2048x1024), K=2048, fp32 out
    gemm_p<2, 4, 2><<<dim3(HIDDEN / 128, SEQ / 256, BATCH), blk256, 0, stream>>>(
        S, vt, h, bo, x, SEQ, SEQ, HIDDEN, SEQ, 1.0f,
        (long)SEQ * SEQ, (long)HIDDEN * SEQ, (long)SEQ * HIDDEN);

    layernorm_out<<<dim3(BS), blk256, 0, stream>>>(h, gamma, beta, out);
}

// Round 5
// 208.441 us; speedup vs baseline: 1.3160x; 1.0153x over previous
//
#include <hip/hip_runtime.h>

typedef __bf16 bf16;
typedef __bf16 bf16x8 __attribute__((ext_vector_type(8)));
typedef __bf16 bf16x4 __attribute__((ext_vector_type(4)));
typedef float floatx4 __attribute__((ext_vector_type(4)));

#define HIDDEN 1024
#define SEQ 2048
#define BATCH 4
#define ATT_SCALE 0.0625f
#define LN_EPS 1e-5f

__device__ __forceinline__ void gload_lds16(const void* g, void* l) {
    __builtin_amdgcn_global_load_lds(
        (const __attribute__((address_space(1))) unsigned int*)g,
        (__attribute__((address_space(3))) unsigned int*)l, 16, 0, 0);
}

#define GBAR() asm volatile("s_barrier" ::: "memory")
#define MFMA(a, b, c) __builtin_amdgcn_mfma_f32_16x16x32_bf16(a, b, c, 0, 0, 0)

// ---------------- fp32 -> bf16 conversion ----------------
__global__ void cvt_f32_bf16(const float* __restrict__ in, bf16* __restrict__ out, int n4) {
    int i = blockIdx.x * blockDim.x + threadIdx.x;
    if (i >= n4) return;
    float4 v = ((const float4*)in)[i];
    bf16x4 o;
    o[0] = (bf16)v.x; o[1] = (bf16)v.y; o[2] = (bf16)v.z; o[3] = (bf16)v.w;
    ((bf16x4*)out)[i] = o;
}

// Wq,Wk -> wqkv rows 0..2047 ; Wo -> wo
__global__ void cvt_weights(const float* __restrict__ Wq, const float* __restrict__ Wk,
                            const float* __restrict__ Wo,
                            bf16* __restrict__ wqkv, bf16* __restrict__ wo) {
    const int NW = HIDDEN * HIDDEN / 4;
    int i = blockIdx.x * blockDim.x + threadIdx.x;
    const float* src; bf16* dst; int j;
    if (i < NW)          { src = Wq; dst = wqkv;                   j = i; }
    else if (i < 2 * NW) { src = Wk; dst = wqkv + HIDDEN * HIDDEN; j = i - NW; }
    else                 { src = Wo; dst = wo;                     j = i - 2 * NW; }
    float4 v = ((const float4*)src)[j];
    bf16x4 o;
    o[0] = (bf16)v.x; o[1] = (bf16)v.y; o[2] = (bf16)v.z; o[3] = (bf16)v.w;
    ((bf16x4*)dst)[j] = o;
}

// Wv (1024x1024 fp32) -> wvT (1024x1024 bf16, transposed)
__global__ void transpose_w(const float* __restrict__ in, bf16* __restrict__ out) {
    __shared__ __attribute__((aligned(16))) bf16 tile[64][72];
    const int d0 = blockIdx.x * 64;
    const int f0 = blockIdx.y * 64;
    const int t = threadIdx.x;
    const int r = t >> 4;
    const int c = (t & 15) * 4;
#pragma unroll
    for (int i = 0; i < 4; ++i) {
        float4 v = *(const float4*)&in[(long)(f0 + r + i * 16) * HIDDEN + d0 + c];
        bf16x4 b;
        b[0] = (bf16)v.x; b[1] = (bf16)v.y; b[2] = (bf16)v.z; b[3] = (bf16)v.w;
        *(bf16x4*)&tile[r + i * 16][c] = b;
    }
    __syncthreads();
#pragma unroll
    for (int i = 0; i < 4; ++i) {
        const int dr = r + i * 16;
        bf16x4 o;
#pragma unroll
        for (int j = 0; j < 4; ++j) o[j] = tile[c + j][dr];
        *(bf16x4*)&out[(long)(d0 + dr) * HIDDEN + f0 + c] = o;
    }
}

// ---------------- GEMM: C = A (MxK) * B^T (B is NxK), bf16 inputs ----------------
// 256 threads = 4 waves (2M x 2N), BM=256, BN=128, wave tile 128x64.
// RING-slot LDS ring of kk-halves (BK=32). 64B rows with 16B-chunk rotation
// ((row>>1)&3) -> conflict-free ds_read_b128; global_load_lds dest linear,
// source carries the inverse chunk permutation (both-sides rule).
// Stage-ahead RING-2 phases, steady-state vmcnt((RING-2)*NU).
// MODE 0: bf16 C = acc*scale ; MODE 2: fp32 C = acc + bias[col] + resid (z-offset)
template <int RING, int MODE>
__global__ __launch_bounds__(256, (RING == 3 ? 2 : 1))
void gemm_p(const bf16* A, const bf16* Bw, void* __restrict__ Cout,
            const float* __restrict__ bias, const float* __restrict__ resid,
            int lda, int ldb, int ldc, int K, float scale,
            long sA, long sB, long sC) {
    constexpr int ABY = 16384;   // A kk-half bytes (256 rows x 64B)
    constexpr int BBY = 8192;    // B kk-half bytes (128 rows x 64B)
    constexpr int SLOT = ABY + BBY;
    constexpr int T16 = 4096;    // 256 threads x 16B
    constexpr int NU = SLOT / T16;   // 6 loads / thread / slot
    constexpr int AU = ABY / T16;    // 4 of them A
    constexpr int VW = (RING - 2) * NU;

    __shared__ __attribute__((aligned(16))) char lds[RING * SLOT];

    // XCD-aware block swizzle (nb % 8 == 0 for all big launches)
    const int gx = gridDim.x;
    const int nb = gx * gridDim.y;
    const int bid = blockIdx.y * gx + blockIdx.x;
    const int cpx = nb >> 3;
    const int sbid = (nb & 7) ? bid : (bid & 7) * cpx + (bid >> 3);
    const int bx = sbid % gx, by = sbid / gx;

    const int z = blockIdx.z;
    const char* Ab = (const char*)(A + (long)z * sA);
    const char* Bb = (const char*)(Bw + (long)z * sB);
    const long lda2 = lda * 2L, ldb2 = ldb * 2L;

    const int t = threadIdx.x;
    const int lane = t & 63;
    const int w = t >> 6;
    const int wm = w >> 1;      // 0..1
    const int wn = w & 1;       // 0..1
    const int l15 = lane & 15;
    const int l4 = lane >> 4;

    const int row0 = by * 256;
    const int col0 = bx * 128;

    // staging sources with inverse chunk rotation
    const char* srcs[NU];
#pragma unroll
    for (int u = 0; u < NU; ++u) {
        int pl = u * T16 + t * 16;
        if (u < AU) {
            int lrow = pl >> 6;
            int c = (((pl >> 4) & 3) - ((lrow >> 1) & 3)) & 3;
            srcs[u] = Ab + (long)(row0 + lrow) * lda2 + c * 16;
        } else {
            int pb = pl - ABY;
            int lrow = pb >> 6;
            int c = (((pb >> 4) & 3) - ((lrow >> 1) & 3)) & 3;
            srcs[u] = Bb + (long)(col0 + lrow) * ldb2 + c * 16;
        }
    }
    const int ld16 = t * 16;

    auto STAGE = [&](int slot, long koff) {
        char* base = &lds[slot * SLOT];
#pragma unroll
        for (int u = 0; u < NU; ++u)
            gload_lds16(srcs[u] + koff, base + u * T16 + ld16);
    };
    auto KOFF = [](int p) { return (long)(p >> 1) * 128 + (long)(p & 1) * 64; };

    floatx4 acc[8][4] = {};
    const int nk = K / 64, np = 2 * nk;

    // prologue: stage phases 0..RING-2
#pragma unroll
    for (int r = 0; r < RING - 1; ++r) STAGE(r, KOFF(r));
    asm volatile("s_waitcnt vmcnt(%0)" :: "n"(VW) : "memory");
    GBAR();

    int slot = 0;
    for (int pp = 0; pp < np; ++pp) {
        const char* sb = &lds[slot * SLOT];
        bf16x8 af[8], bfr[4];
#pragma unroll
        for (int m = 0; m < 8; ++m) {
            int lr = wm * 128 + m * 16 + l15;
            int p = (l4 + ((lr >> 1) & 3)) & 3;
            af[m] = *(const bf16x8*)(sb + lr * 64 + p * 16);
        }
#pragma unroll
        for (int n = 0; n < 4; ++n) {
            int lr = wn * 64 + n * 16 + l15;
            int p = (l4 + ((lr >> 1) & 3)) & 3;
            bfr[n] = *(const bf16x8*)(sb + ABY + lr * 64 + p * 16);
        }

        const int pf = pp + RING - 1;
        int s2 = slot + RING - 1; if (s2 >= RING) s2 -= RING;
        if (pf < np) STAGE(s2, KOFF(pf));

        __builtin_amdgcn_s_setprio(1);
#pragma unroll
        for (int m = 0; m < 8; ++m)
#pragma unroll
            for (int n = 0; n < 4; ++n)
                acc[m][n] = MFMA(af[m], bfr[n], acc[m][n]);
        __builtin_amdgcn_s_setprio(0);

        asm volatile("s_waitcnt lgkmcnt(0)" ::: "memory");
        if (pf < np) asm volatile("s_waitcnt vmcnt(%0)" :: "n"(VW) : "memory");
        else         asm volatile("s_waitcnt vmcnt(0)" ::: "memory");
        GBAR();
        slot = (slot == RING - 1) ? 0 : slot + 1;
    }

    // ---- epilogue
    const int rq = l4 * 4;
    if constexpr (MODE == 0) {
        bf16* C = ((bf16*)Cout) + (long)z * sC;
#pragma unroll
        for (int m = 0; m < 8; ++m)
#pragma unroll
            for (int i = 0; i < 4; ++i) {
                long gr = row0 + wm * 128 + m * 16 + rq + i;
#pragma unroll
                for (int n = 0; n < 4; ++n) {
                    int gc = col0 + wn * 64 + n * 16 + l15;
                    C[gr * ldc + gc] = (bf16)(acc[m][n][i] * scale);
                }
            }
    } else {
        float* C = (float*)Cout + (long)z * sC;
        const float* R = resid + (long)z * sC;
#pragma unroll
        for (int m = 0; m < 8; ++m)
#pragma unroll
            for (int i = 0; i < 4; ++i) {
                long gr = row0 + wm * 128 + m * 16 + rq + i;
#pragma unroll
                for (int n = 0; n < 4; ++n) {
                    int gc = col0 + wn * 64 + n * 16 + l15;
                    C[gr * ldc + gc] = acc[m][n][i] + bias[gc] + R[gr * ldc + gc];
                }
            }
    }
}

// ---------------- transpose VWc (from fused qkv): per batch (SEQ x 1024 @ld 3072) -> (1024 x SEQ) ----------------
__global__ void transpose_v(const bf16* __restrict__ qkv, bf16* __restrict__ out) {
    __shared__ __attribute__((aligned(16))) bf16 tile[64][72];
    const int z = blockIdx.z;
    const bf16* ib = qkv + (long)z * SEQ * 3072 + 2048;
    bf16* ob = out + (long)z * SEQ * HIDDEN;
    const int d0 = blockIdx.x * 64;
    const int s0 = blockIdx.y * 64;
    const int t = threadIdx.x;
    const int r = t >> 4;
    const int c = (t & 15) * 4;
#pragma unroll
    for (int i = 0; i < 4; ++i) {
        bf16x4 v = *(const bf16x4*)&ib[(long)(s0 + r + i * 16) * 3072 + d0 + c];
        *(bf16x4*)&tile[r + i * 16][c] = v;
    }
    __syncthreads();
#pragma unroll
    for (int i = 0; i < 4; ++i) {
        const int dr = r + i * 16;
        bf16x4 o;
#pragma unroll
        for (int j = 0; j < 4; ++j) o[j] = tile[c + j][dr];
        *(bf16x4*)&ob[(long)(d0 + dr) * SEQ + s0 + c] = o;
    }
}

// ---------------- row softmax, in-place on bf16 scores ----------------
__global__ void softmax_rows(bf16* __restrict__ S, const int* __restrict__ mask) {
    const int b = blockIdx.y;
    const int row = blockIdx.x;
    bf16* srow = S + ((long)b * SEQ + row) * SEQ;
    const int* mrow = mask + b * SEQ;
    const int t = threadIdx.x;

    bf16x8 sv = *(const bf16x8*)&srow[t * 8];
    int4 m0 = ((const int4*)mrow)[t * 2];
    int4 m1 = ((const int4*)mrow)[t * 2 + 1];
    int mk[8] = {m0.x, m0.y, m0.z, m0.w, m1.x, m1.y, m1.z, m1.w};

    float v[8];
    float mx = -1e30f;
#pragma unroll
    for (int j = 0; j < 8; ++j) {
        float s = (float)sv[j];
        if (mk[j] == 0) s = -1e9f;
        v[j] = s;
        mx = fmaxf(mx, s);
    }
    __shared__ float redm[4], reds[4];
#pragma unroll
    for (int off = 32; off > 0; off >>= 1) mx = fmaxf(mx, __shfl_down(mx, off));
    if ((t & 63) == 0) redm[t >> 6] = mx;
    __syncthreads();
    mx = fmaxf(fmaxf(redm[0], redm[1]), fmaxf(redm[2], redm[3]));

    float sum = 0.f;
#pragma unroll
    for (int j = 0; j < 8; ++j) {
        v[j] = __expf(v[j] - mx);
        sum += v[j];
    }
#pragma unroll
    for (int off = 32; off > 0; off >>= 1) sum += __shfl_down(sum, off);
    if ((t & 63) == 0) reds[t >> 6] = sum;
    __syncthreads();
    sum = reds[0] + reds[1] + reds[2] + reds[3];
    float inv = 1.0f / sum;

    bf16x8 o;
#pragma unroll
    for (int j = 0; j < 8; ++j) o[j] = (bf16)(v[j] * inv);
    *(bf16x8*)&srow[t * 8] = o;
}

// ---------------- LayerNorm: h (fp32) -> out (fp32) ----------------
__global__ void layernorm_out(const float* __restrict__ h, const float* __restrict__ gamma,
                              const float* __restrict__ beta, float* __restrict__ out) {
    const long row = blockIdx.x;
    const float* hr = h + row * HIDDEN;
    const int t = threadIdx.x;
    float4 v = ((const float4*)hr)[t];
    float s = v.x + v.y + v.z + v.w;
    float sq = v.x * v.x + v.y * v.y + v.z * v.z + v.w * v.w;
    __shared__ float rs[4], rq[4];
#pragma unroll
    for (int off = 32; off > 0; off >>= 1) {
        s += __shfl_down(s, off);
        sq += __shfl_down(sq, off);
    }
    if ((t & 63) == 0) { rs[t >> 6] = s; rq[t >> 6] = sq; }
    __syncthreads();
    s = rs[0] + rs[1] + rs[2] + rs[3];
    sq = rq[0] + rq[1] + rq[2] + rq[3];
    float mu = s * (1.0f / HIDDEN);
    float var = sq * (1.0f / HIDDEN) - mu * mu;
    float rinv = rsqrtf(var + LN_EPS);
    float4 g = ((const float4*)gamma)[t];
    float4 bt = ((const float4*)beta)[t];
    float4 o;
    o.x = (v.x - mu) * rinv * g.x + bt.x;
    o.y = (v.y - mu) * rinv * g.y + bt.y;
    o.z = (v.z - mu) * rinv * g.z + bt.z;
    o.w = (v.w - mu) * rinv * g.w + bt.w;
    ((float4*)(out + row * HIDDEN))[t] = o;
}

// ---------------- launch ----------------
extern "C" void kernel_launch(void* const* d_in, const int* in_sizes, int n_in,
                              void* d_out, int out_size, void* d_ws, size_t ws_size,
                              hipStream_t stream) {
    const float* x     = (const float*)d_in[0];
    const int*   mask  = (const int*)d_in[1];
    const float* Wq    = (const float*)d_in[2];
    const float* Wk    = (const float*)d_in[3];
    const float* Wv    = (const float*)d_in[4];
    const float* Wo    = (const float*)d_in[5];
    const float* bo    = (const float*)d_in[6];
    const float* gamma = (const float*)d_in[7];
    const float* beta  = (const float*)d_in[8];
    float* out = (float*)d_out;

    char* ws = (char*)d_ws;
    const long MB = 1024L * 1024L;
    bf16* qkv  = (bf16*)(ws + 0 * MB);    // 48 MB (8192 x 3072) [Q|K|VWc]
    bf16* xb   = (bf16*)(ws + 48 * MB);   // 16 MB; vt reuses after QKV
    bf16* vt   = (bf16*)(ws + 48 * MB);   // 16 MB (per batch 1024 x 2048)
    bf16* wqkv = (bf16*)(ws + 64 * MB);   // 6 MB: Wq,Wk,Wc rows
    bf16* wo   = (bf16*)(ws + 70 * MB);   // 2 MB
    bf16* wvT  = (bf16*)(ws + 72 * MB);   // 2 MB
    bf16* S    = (bf16*)(ws + 74 * MB);   // 32 MB scores/probs
    float* h   = (float*)(ws + 0 * MB);   // 32 MB over qkv (Q,K dead after scores)

    const int BS = BATCH * SEQ;  // 8192
    dim3 blk256(256);

    cvt_f32_bf16<<<dim3(BS * HIDDEN / 4 / 256), blk256, 0, stream>>>(x, xb, BS * HIDDEN / 4);
    cvt_weights<<<dim3(3 * HIDDEN * HIDDEN / 4 / 256), blk256, 0, stream>>>(Wq, Wk, Wo, wqkv, wo);
    transpose_w<<<dim3(16, 16), blk256, 0, stream>>>(Wv, wvT);

    // Wc = Wo * Wv -> wqkv rows 2048..3071 (B = Wv^T)
    gemm_p<3, 0><<<dim3(1024 / 128, 1024 / 256, 1), blk256, 0, stream>>>(
        wo, wvT, wqkv + 2048 * HIDDEN, nullptr, nullptr,
        HIDDEN, HIDDEN, HIDDEN, HIDDEN, 1.0f, 0, 0, 0);

    // fused QKV+Wc projection: (8192x1024)*(3072x1024)^T -> [Q|K|VWc]  (768 WGs, 2/CU)
    gemm_p<3, 0><<<dim3(3072 / 128, BS / 256, 1), blk256, 0, stream>>>(
        xb, wqkv, qkv, nullptr, nullptr, HIDDEN, HIDDEN, 3072, HIDDEN, 1.0f, 0, 0, 0);

    // VWc -> vt per batch
    transpose_v<<<dim3(HIDDEN / 64, SEQ / 64, BATCH), blk256, 0, stream>>>(qkv, vt);

    // scores: per batch (2048x2048) = q*k^T*SCALE  (512 WGs, 2/CU)
    gemm_p<3, 0><<<dim3(SEQ / 128, SEQ / 256, BATCH), blk256, 0, stream>>>(
        qkv, qkv + 1024, S, nullptr, nullptr, 3072, 3072, SEQ, HIDDEN, ATT_SCALE,
        (long)SEQ * 3072, (long)SEQ * 3072, (long)SEQ * SEQ);

    softmax_rows<<<dim3(SEQ, BATCH), blk256, 0, stream>>>(S, mask);

    // h = P * vt^T + bo + x : per batch (2048x1024), K=2048, fp32 out
    // RING=4 (96 KB LDS -> exactly 1 block/CU, 256 WGs spread over all CUs; depth-2 pipeline)
    gemm_p<4, 2><<<dim3(HIDDEN / 128, SEQ / 256, BATCH), blk256, 0, stream>>>(
        S, vt, h, bo, x, SEQ, SEQ, HIDDEN, SEQ, 1.0f,
        (long)SEQ * SEQ, (long)HIDDEN * SEQ, (long)SEQ * HIDDEN);

    layernorm_out<<<dim3(BS), blk256, 0, stream>>>(h, gamma, beta, out);
}

// Round 6
// 207.081 us; speedup vs baseline: 1.3246x; 1.0066x over previous
//
#include <hip/hip_runtime.h>

typedef __bf16 bf16;
typedef __bf16 bf16x8 __attribute__((ext_vector_type(8)));
typedef __bf16 bf16x4 __attribute__((ext_vector_type(4)));
typedef float floatx4 __attribute__((ext_vector_type(4)));

#define HIDDEN 1024
#define SEQ 2048
#define BATCH 4
#define ATT_SCALE 0.0625f
#define LN_EPS 1e-5f

__device__ __forceinline__ void gload_lds16(const void* g, void* l) {
    __builtin_amdgcn_global_load_lds(
        (const __attribute__((address_space(1))) unsigned int*)g,
        (__attribute__((address_space(3))) unsigned int*)l, 16, 0, 0);
}

#define GBAR() asm volatile("s_barrier" ::: "memory")
#define MFMA(a, b, c) __builtin_amdgcn_mfma_f32_16x16x32_bf16(a, b, c, 0, 0, 0)

// ---------------- fp32 -> bf16 conversion ----------------
__global__ void cvt_f32_bf16(const float* __restrict__ in, bf16* __restrict__ out, int n4) {
    int i = blockIdx.x * blockDim.x + threadIdx.x;
    if (i >= n4) return;
    float4 v = ((const float4*)in)[i];
    bf16x4 o;
    o[0] = (bf16)v.x; o[1] = (bf16)v.y; o[2] = (bf16)v.z; o[3] = (bf16)v.w;
    ((bf16x4*)out)[i] = o;
}

// Wq,Wk -> wqkv rows 0..2047 ; Wo -> wo
__global__ void cvt_weights(const float* __restrict__ Wq, const float* __restrict__ Wk,
                            const float* __restrict__ Wo,
                            bf16* __restrict__ wqkv, bf16* __restrict__ wo) {
    const int NW = HIDDEN * HIDDEN / 4;
    int i = blockIdx.x * blockDim.x + threadIdx.x;
    const float* src; bf16* dst; int j;
    if (i < NW)          { src = Wq; dst = wqkv;                   j = i; }
    else if (i < 2 * NW) { src = Wk; dst = wqkv + HIDDEN * HIDDEN; j = i - NW; }
    else                 { src = Wo; dst = wo;                     j = i - 2 * NW; }
    float4 v = ((const float4*)src)[j];
    bf16x4 o;
    o[0] = (bf16)v.x; o[1] = (bf16)v.y; o[2] = (bf16)v.z; o[3] = (bf16)v.w;
    ((bf16x4*)dst)[j] = o;
}

// Wv (1024x1024 fp32) -> wvT (1024x1024 bf16, transposed)
__global__ void transpose_w(const float* __restrict__ in, bf16* __restrict__ out) {
    __shared__ __attribute__((aligned(16))) bf16 tile[64][72];
    const int d0 = blockIdx.x * 64;
    const int f0 = blockIdx.y * 64;
    const int t = threadIdx.x;
    const int r = t >> 4;
    const int c = (t & 15) * 4;
#pragma unroll
    for (int i = 0; i < 4; ++i) {
        float4 v = *(const float4*)&in[(long)(f0 + r + i * 16) * HIDDEN + d0 + c];
        bf16x4 b;
        b[0] = (bf16)v.x; b[1] = (bf16)v.y; b[2] = (bf16)v.z; b[3] = (bf16)v.w;
        *(bf16x4*)&tile[r + i * 16][c] = b;
    }
    __syncthreads();
#pragma unroll
    for (int i = 0; i < 4; ++i) {
        const int dr = r + i * 16;
        bf16x4 o;
#pragma unroll
        for (int j = 0; j < 4; ++j) o[j] = tile[c + j][dr];
        *(bf16x4*)&out[(long)(d0 + dr) * HIDDEN + f0 + c] = o;
    }
}

// ---------------- GEMM: C = A (MxK) * B^T (B is NxK), bf16 inputs ----------------
// 512 threads = 8 waves (WM x WN). Wave tile (MR*16) x (NR*16). BM=WM*MR*16, BN=WN*NR*16.
// 4-slot LDS ring of kk-halves (BK=32, 64B rows, 16B-chunk rotation (row>>1)&3 ->
// measured-zero bank conflicts; global_load_lds dest linear, source inverse-permuted).
// Stage-ahead 2 slots; counted vmcnt(UPS) once per slot. SPLIT=1: two 16-MFMA
// sub-phases per slot (m201 8-phase schedule). MODE 0: bf16 C=acc*scale ;
// MODE 2: fp32 C = acc + bias[col] + resid (z-offset strides).
template <int WM, int WN, int MR, int NR, int SPLIT, int MODE>
__global__ __launch_bounds__(512, 2)
void gemm_t(const bf16* A, const bf16* Bw, void* __restrict__ Cout,
            const float* __restrict__ bias, const float* __restrict__ resid,
            int lda, int ldb, int ldc, int K, float scale,
            long sA, long sB, long sC) {
    constexpr int BM = WM * MR * 16;
    constexpr int BN = WN * NR * 16;
    constexpr int ABY = BM * 64;
    constexpr int SLOT = (BM + BN) * 64;
    constexpr int UPS = SLOT / 8192;       // gload units per slot
    constexpr int U0 = (UPS + 1) / 2;
    constexpr int MH = SPLIT ? MR / 2 : MR;

    __shared__ __attribute__((aligned(16))) char lds[4 * SLOT];

    // XCD-aware block swizzle (all grids have nb % 8 == 0)
    const int gx = gridDim.x;
    const int nblk = gx * gridDim.y;
    const int bid = blockIdx.y * gx + blockIdx.x;
    const int cpx = nblk >> 3;
    const int sbid = (nblk & 7) ? bid : (bid & 7) * cpx + (bid >> 3);
    const int bx = sbid % gx, by = sbid / gx;

    const int z = blockIdx.z;
    const char* Ab = (const char*)(A + (long)z * sA);
    const char* Bb = (const char*)(Bw + (long)z * sB);
    const long lda2 = lda * 2L, ldb2 = ldb * 2L;

    const int t = threadIdx.x;
    const int lane = t & 63;
    const int w = t >> 6;
    const int wm = w / WN, wn = w % WN;
    const int l15 = lane & 15;
    const int l4 = lane >> 4;

    const int row0 = by * BM;
    const int col0 = bx * BN;

    // staging sources with inverse chunk rotation
    const char* srcs[UPS];
#pragma unroll
    for (int u = 0; u < UPS; ++u) {
        int pl = u * 8192 + t * 16;
        if (pl < ABY) {
            int lrow = pl >> 6;
            int c = (((pl >> 4) & 3) - ((lrow >> 1) & 3)) & 3;
            srcs[u] = Ab + (long)(row0 + lrow) * lda2 + c * 16;
        } else {
            int pb = pl - ABY;
            int lrow = pb >> 6;
            int c = (((pb >> 4) & 3) - ((lrow >> 1) & 3)) & 3;
            srcs[u] = Bb + (long)(col0 + lrow) * ldb2 + c * 16;
        }
    }
    const int ld16 = t * 16;

    auto STAGE = [&](char* base, long koff, int ulo, int uhi) {
#pragma unroll
        for (int u = 0; u < UPS; ++u)
            if (u >= ulo && u < uhi)
                gload_lds16(srcs[u] + koff, base + u * 8192 + ld16);
    };

    floatx4 acc[MR][NR] = {};
    const int ns = K / 32;

    // prologue: slots 0,1
    STAGE(&lds[0], 0, 0, UPS);
    STAGE(&lds[SLOT], 64, 0, UPS);
    asm volatile("s_waitcnt vmcnt(%0)" :: "n"(UPS) : "memory");
    GBAR();

    for (int s = 0; s < ns; ++s) {
        const char* sb = &lds[(s & 3) * SLOT];
        char* nbuf = &lds[((s + 2) & 3) * SLOT];
        const long koff = (long)((s + 2 < ns) ? (s + 2) : (ns - 1)) * 64;

        // ---- sub-phase 0: B frags + first MH A frags
        bf16x8 bfr[NR], af[MH];
#pragma unroll
        for (int n = 0; n < NR; ++n) {
            int lr = wn * (NR * 16) + n * 16 + l15;
            int p = (l4 + ((lr >> 1) & 3)) & 3;
            bfr[n] = *(const bf16x8*)(sb + ABY + lr * 64 + p * 16);
        }
#pragma unroll
        for (int m = 0; m < MH; ++m) {
            int lr = wm * (MR * 16) + m * 16 + l15;
            int p = (l4 + ((lr >> 1) & 3)) & 3;
            af[m] = *(const bf16x8*)(sb + lr * 64 + p * 16);
        }
        STAGE(nbuf, koff, 0, SPLIT ? U0 : UPS);
        GBAR();
        asm volatile("s_waitcnt lgkmcnt(0)" ::: "memory");
        __builtin_amdgcn_s_setprio(1);
#pragma unroll
        for (int m = 0; m < MH; ++m)
#pragma unroll
            for (int n = 0; n < NR; ++n)
                acc[m][n] = MFMA(af[m], bfr[n], acc[m][n]);
        __builtin_amdgcn_s_setprio(0);

        if constexpr (SPLIT) {
            GBAR();
            // ---- sub-phase 1: remaining A frags, reuse bfr
            bf16x8 ag[MR - MH];
#pragma unroll
            for (int m = 0; m < MR - MH; ++m) {
                int lr = wm * (MR * 16) + (MH + m) * 16 + l15;
                int p = (l4 + ((lr >> 1) & 3)) & 3;
                ag[m] = *(const bf16x8*)(sb + lr * 64 + p * 16);
            }
            STAGE(nbuf, koff, U0, UPS);
            GBAR();
            asm volatile("s_waitcnt lgkmcnt(0)" ::: "memory");
            __builtin_amdgcn_s_setprio(1);
#pragma unroll
            for (int m = 0; m < MR - MH; ++m)
#pragma unroll
                for (int n = 0; n < NR; ++n)
                    acc[MH + m][n] = MFMA(ag[m], bfr[n], acc[MH + m][n]);
            __builtin_amdgcn_s_setprio(0);
        }

        asm volatile("s_waitcnt vmcnt(%0)" :: "n"(UPS) : "memory");
        GBAR();
    }
    asm volatile("s_waitcnt vmcnt(0)" ::: "memory");

    // ---- epilogue
    const int rq = l4 * 4;
    if constexpr (MODE == 0) {
        bf16* C = ((bf16*)Cout) + (long)z * sC;
#pragma unroll
        for (int m = 0; m < MR; ++m)
#pragma unroll
            for (int i = 0; i < 4; ++i) {
                long gr = row0 + wm * (MR * 16) + m * 16 + rq + i;
#pragma unroll
                for (int n = 0; n < NR; ++n) {
                    int gc = col0 + wn * (NR * 16) + n * 16 + l15;
                    C[gr * ldc + gc] = (bf16)(acc[m][n][i] * scale);
                }
            }
    } else {
        float* C = (float*)Cout + (long)z * sC;
        const float* R = resid + (long)z * sC;
#pragma unroll
        for (int m = 0; m < MR; ++m)
#pragma unroll
            for (int i = 0; i < 4; ++i) {
                long gr = row0 + wm * (MR * 16) + m * 16 + rq + i;
#pragma unroll
                for (int n = 0; n < NR; ++n) {
                    int gc = col0 + wn * (NR * 16) + n * 16 + l15;
                    C[gr * ldc + gc] = acc[m][n][i] + bias[gc] + R[gr * ldc + gc];
                }
            }
    }
}

// ---------------- transpose VWc (from fused qkv): per batch (SEQ x 1024 @ld 3072) -> (1024 x SEQ) ----------------
__global__ void transpose_v(const bf16* __restrict__ qkv, bf16* __restrict__ out) {
    __shared__ __attribute__((aligned(16))) bf16 tile[64][72];
    const int z = blockIdx.z;
    const bf16* ib = qkv + (long)z * SEQ * 3072 + 2048;
    bf16* ob = out + (long)z * SEQ * HIDDEN;
    const int d0 = blockIdx.x * 64;
    const int s0 = blockIdx.y * 64;
    const int t = threadIdx.x;
    const int r = t >> 4;
    const int c = (t & 15) * 4;
#pragma unroll
    for (int i = 0; i < 4; ++i) {
        bf16x4 v = *(const bf16x4*)&ib[(long)(s0 + r + i * 16) * 3072 + d0 + c];
        *(bf16x4*)&tile[r + i * 16][c] = v;
    }
    __syncthreads();
#pragma unroll
    for (int i = 0; i < 4; ++i) {
        const int dr = r + i * 16;
        bf16x4 o;
#pragma unroll
        for (int j = 0; j < 4; ++j) o[j] = tile[c + j][dr];
        *(bf16x4*)&ob[(long)(d0 + dr) * SEQ + s0 + c] = o;
    }
}

// ---------------- row softmax, in-place on bf16 scores ----------------
__global__ void softmax_rows(bf16* __restrict__ S, const int* __restrict__ mask) {
    const int b = blockIdx.y;
    const int row = blockIdx.x;
    bf16* srow = S + ((long)b * SEQ + row) * SEQ;
    const int* mrow = mask + b * SEQ;
    const int t = threadIdx.x;

    bf16x8 sv = *(const bf16x8*)&srow[t * 8];
    int4 m0 = ((const int4*)mrow)[t * 2];
    int4 m1 = ((const int4*)mrow)[t * 2 + 1];
    int mk[8] = {m0.x, m0.y, m0.z, m0.w, m1.x, m1.y, m1.z, m1.w};

    float v[8];
    float mx = -1e30f;
#pragma unroll
    for (int j = 0; j < 8; ++j) {
        float s = (float)sv[j];
        if (mk[j] == 0) s = -1e9f;
        v[j] = s;
        mx = fmaxf(mx, s);
    }
    __shared__ float redm[4], reds[4];
#pragma unroll
    for (int off = 32; off > 0; off >>= 1) mx = fmaxf(mx, __shfl_down(mx, off));
    if ((t & 63) == 0) redm[t >> 6] = mx;
    __syncthreads();
    mx = fmaxf(fmaxf(redm[0], redm[1]), fmaxf(redm[2], redm[3]));

    float sum = 0.f;
#pragma unroll
    for (int j = 0; j < 8; ++j) {
        v[j] = __expf(v[j] - mx);
        sum += v[j];
    }
#pragma unroll
    for (int off = 32; off > 0; off >>= 1) sum += __shfl_down(sum, off);
    if ((t & 63) == 0) reds[t >> 6] = sum;
    __syncthreads();
    sum = reds[0] + reds[1] + reds[2] + reds[3];
    float inv = 1.0f / sum;

    bf16x8 o;
#pragma unroll
    for (int j = 0; j < 8; ++j) o[j] = (bf16)(v[j] * inv);
    *(bf16x8*)&srow[t * 8] = o;
}

// ---------------- LayerNorm: h (fp32) -> out (fp32) ----------------
__global__ void layernorm_out(const float* __restrict__ h, const float* __restrict__ gamma,
                              const float* __restrict__ beta, float* __restrict__ out) {
    const long row = blockIdx.x;
    const float* hr = h + row * HIDDEN;
    const int t = threadIdx.x;
    float4 v = ((const float4*)hr)[t];
    float s = v.x + v.y + v.z + v.w;
    float sq = v.x * v.x + v.y * v.y + v.z * v.z + v.w * v.w;
    __shared__ float rs[4], rq[4];
#pragma unroll
    for (int off = 32; off > 0; off >>= 1) {
        s += __shfl_down(s, off);
        sq += __shfl_down(sq, off);
    }
    if ((t & 63) == 0) { rs[t >> 6] = s; rq[t >> 6] = sq; }
    __syncthreads();
    s = rs[0] + rs[1] + rs[2] + rs[3];
    sq = rq[0] + rq[1] + rq[2] + rq[3];
    float mu = s * (1.0f / HIDDEN);
    float var = sq * (1.0f / HIDDEN) - mu * mu;
    float rinv = rsqrtf(var + LN_EPS);
    float4 g = ((const float4*)gamma)[t];
    float4 bt = ((const float4*)beta)[t];
    float4 o;
    o.x = (v.x - mu) * rinv * g.x + bt.x;
    o.y = (v.y - mu) * rinv * g.y + bt.y;
    o.z = (v.z - mu) * rinv * g.z + bt.z;
    o.w = (v.w - mu) * rinv * g.w + bt.w;
    ((float4*)(out + row * HIDDEN))[t] = o;
}

// ---------------- launch ----------------
extern "C" void kernel_launch(void* const* d_in, const int* in_sizes, int n_in,
                              void* d_out, int out_size, void* d_ws, size_t ws_size,
                              hipStream_t stream) {
    const float* x     = (const float*)d_in[0];
    const int*   mask  = (const int*)d_in[1];
    const float* Wq    = (const float*)d_in[2];
    const float* Wk    = (const float*)d_in[3];
    const float* Wv    = (const float*)d_in[4];
    const float* Wo    = (const float*)d_in[5];
    const float* bo    = (const float*)d_in[6];
    const float* gamma = (const float*)d_in[7];
    const float* beta  = (const float*)d_in[8];
    float* out = (float*)d_out;

    char* ws = (char*)d_ws;
    const long MB = 1024L * 1024L;
    bf16* qkv  = (bf16*)(ws + 0 * MB);    // 48 MB (8192 x 3072) [Q|K|VWc]
    bf16* xb   = (bf16*)(ws + 48 * MB);   // 16 MB; vt reuses after QKV
    bf16* vt   = (bf16*)(ws + 48 * MB);   // 16 MB (per batch 1024 x 2048)
    bf16* wqkv = (bf16*)(ws + 64 * MB);   // 6 MB: Wq,Wk,Wc rows
    bf16* wo   = (bf16*)(ws + 70 * MB);   // 2 MB
    bf16* wvT  = (bf16*)(ws + 72 * MB);   // 2 MB
    bf16* S    = (bf16*)(ws + 74 * MB);   // 32 MB scores/probs
    float* h   = (float*)(ws + 0 * MB);   // 32 MB over qkv (Q,K dead after scores)

    const int BS = BATCH * SEQ;  // 8192
    dim3 blk256(256), blk512(512);

    cvt_f32_bf16<<<dim3(BS * HIDDEN / 4 / 256), blk256, 0, stream>>>(x, xb, BS * HIDDEN / 4);
    cvt_weights<<<dim3(3 * HIDDEN * HIDDEN / 4 / 256), blk256, 0, stream>>>(Wq, Wk, Wo, wqkv, wo);
    transpose_w<<<dim3(16, 16), blk256, 0, stream>>>(Wv, wvT);

    // Wc = Wo * Wv -> wqkv rows 2048..3071 (B = Wv^T) : 128x128 tile, 64 WGs
    gemm_t<2, 4, 4, 2, 0, 0><<<dim3(8, 8, 1), blk512, 0, stream>>>(
        wo, wvT, wqkv + 2048 * HIDDEN, nullptr, nullptr,
        HIDDEN, HIDDEN, HIDDEN, HIDDEN, 1.0f, 0, 0, 0);

    // fused QKV+Wc projection: (8192x1024)*(3072x1024)^T -> [Q|K|VWc]  (256² tile, 384 WGs)
    gemm_t<2, 4, 8, 4, 1, 0><<<dim3(3072 / 256, BS / 256, 1), blk512, 0, stream>>>(
        xb, wqkv, qkv, nullptr, nullptr, HIDDEN, HIDDEN, 3072, HIDDEN, 1.0f, 0, 0, 0);

    // VWc -> vt per batch
    transpose_v<<<dim3(HIDDEN / 64, SEQ / 64, BATCH), blk256, 0, stream>>>(qkv, vt);

    // scores: per batch (2048x2048) = q*k^T*SCALE  (256² tile, 8x8x4 = 256 WGs)
    gemm_t<2, 4, 8, 4, 1, 0><<<dim3(SEQ / 256, SEQ / 256, BATCH), blk512, 0, stream>>>(
        qkv, qkv + 1024, S, nullptr, nullptr, 3072, 3072, SEQ, HIDDEN, ATT_SCALE,
        (long)SEQ * 3072, (long)SEQ * 3072, (long)SEQ * SEQ);

    softmax_rows<<<dim3(SEQ, BATCH), blk256, 0, stream>>>(S, mask);

    // h = P * vt^T + bo + x : per batch (2048x1024), K=2048, fp32 out
    // 256x128 tile (4Mx2N waves), 8x8x4 = 256 WGs -> full CU coverage
    gemm_t<4, 2, 4, 4, 0, 2><<<dim3(HIDDEN / 128, SEQ / 256, BATCH), blk512, 0, stream>>>(
        S, vt, h, bo, x, SEQ, SEQ, HIDDEN, SEQ, 1.0f,
        (long)SEQ * SEQ, (long)HIDDEN * SEQ, (long)SEQ * HIDDEN);

    layernorm_out<<<dim3(BS), blk256, 0, stream>>>(h, gamma, beta, out);
}

// Round 7
// 191.885 us; speedup vs baseline: 1.4295x; 1.0792x over previous
//
#include <hip/hip_runtime.h>

typedef __bf16 bf16;
typedef __bf16 bf16x8 __attribute__((ext_vector_type(8)));
typedef __bf16 bf16x4 __attribute__((ext_vector_type(4)));
typedef float floatx4 __attribute__((ext_vector_type(4)));

#define HIDDEN 1024
#define SEQ 2048
#define BATCH 4
#define ATT_SCALE 0.0625f
#define LN_EPS 1e-5f

__device__ __forceinline__ void gload_lds16(const void* g, void* l) {
    __builtin_amdgcn_global_load_lds(
        (const __attribute__((address_space(1))) unsigned int*)g,
        (__attribute__((address_space(3))) unsigned int*)l, 16, 0, 0);
}

#define GBAR() asm volatile("s_barrier" ::: "memory")
#define MFMA(a, b, c) __builtin_amdgcn_mfma_f32_16x16x32_bf16(a, b, c, 0, 0, 0)

// ---------------- fp32 -> bf16 conversion ----------------
__global__ void cvt_f32_bf16(const float* __restrict__ in, bf16* __restrict__ out, int n4) {
    int i = blockIdx.x * blockDim.x + threadIdx.x;
    if (i >= n4) return;
    float4 v = ((const float4*)in)[i];
    bf16x4 o;
    o[0] = (bf16)v.x; o[1] = (bf16)v.y; o[2] = (bf16)v.z; o[3] = (bf16)v.w;
    ((bf16x4*)out)[i] = o;
}

// ---------------- transpose 3 weight matrices (fp32 1024x1024 -> bf16 transposed) ----------------
__global__ void transpose_w3(const float* __restrict__ s0, const float* __restrict__ s1,
                             const float* __restrict__ s2,
                             bf16* __restrict__ d0p, bf16* __restrict__ d1p, bf16* __restrict__ d2p) {
    const float* in = (blockIdx.z == 0) ? s0 : (blockIdx.z == 1) ? s1 : s2;
    bf16* out = (blockIdx.z == 0) ? d0p : (blockIdx.z == 1) ? d1p : d2p;
    __shared__ __attribute__((aligned(16))) bf16 tile[64][72];
    const int d0 = blockIdx.x * 64;
    const int f0 = blockIdx.y * 64;
    const int t = threadIdx.x;
    const int r = t >> 4;
    const int c = (t & 15) * 4;
#pragma unroll
    for (int i = 0; i < 4; ++i) {
        float4 v = *(const float4*)&in[(long)(f0 + r + i * 16) * HIDDEN + d0 + c];
        bf16x4 b;
        b[0] = (bf16)v.x; b[1] = (bf16)v.y; b[2] = (bf16)v.z; b[3] = (bf16)v.w;
        *(bf16x4*)&tile[r + i * 16][c] = b;
    }
    __syncthreads();
#pragma unroll
    for (int i = 0; i < 4; ++i) {
        const int dr = r + i * 16;
        bf16x4 o;
#pragma unroll
        for (int j = 0; j < 4; ++j) o[j] = tile[c + j][dr];
        *(bf16x4*)&out[(long)(d0 + dr) * HIDDEN + f0 + c] = o;
    }
}

// ---------------- GEMM: C = A (MxK) * B^T (B is NxK), bf16 inputs ----------------
// 256 threads = 4 waves (2M x 2N), BM=256, BN=128, wave tile 128x64.
// RING-slot LDS ring of kk-halves (BK=32). 64B rows with 16B-chunk rotation
// ((row>>1)&3) -> measured-zero-conflict ds_read_b128; global_load_lds dest
// linear, source carries the inverse chunk permutation (both-sides rule).
// Stage-ahead RING-2 phases, steady-state vmcnt((RING-2)*NU).
// MODE 0: bf16 C = acc*scale ; MODE 2: fp32 C = acc + bias[col] + resid (z-offset)
template <int RING, int MODE>
__global__ __launch_bounds__(256, (RING == 3 ? 2 : 1))
void gemm_p(const bf16* A, const bf16* Bw, void* __restrict__ Cout,
            const float* __restrict__ bias, const float* __restrict__ resid,
            int lda, int ldb, int ldc, int K, float scale,
            long sA, long sB, long sC) {
    constexpr int ABY = 16384;   // A kk-half bytes (256 rows x 64B)
    constexpr int BBY = 8192;    // B kk-half bytes (128 rows x 64B)
    constexpr int SLOT = ABY + BBY;
    constexpr int T16 = 4096;    // 256 threads x 16B
    constexpr int NU = SLOT / T16;   // 6 loads / thread / slot
    constexpr int AU = ABY / T16;    // 4 of them A
    constexpr int VW = (RING - 2) * NU;

    __shared__ __attribute__((aligned(16))) char lds[RING * SLOT];

    // XCD-aware block swizzle (nb % 8 == 0 for all big launches)
    const int gx = gridDim.x;
    const int nb = gx * gridDim.y;
    const int bid = blockIdx.y * gx + blockIdx.x;
    const int cpx = nb >> 3;
    const int sbid = (nb & 7) ? bid : (bid & 7) * cpx + (bid >> 3);
    const int bx = sbid % gx, by = sbid / gx;

    const int z = blockIdx.z;
    const char* Ab = (const char*)(A + (long)z * sA);
    const char* Bb = (const char*)(Bw + (long)z * sB);
    const long lda2 = lda * 2L, ldb2 = ldb * 2L;

    const int t = threadIdx.x;
    const int lane = t & 63;
    const int w = t >> 6;
    const int wm = w >> 1;      // 0..1
    const int wn = w & 1;       // 0..1
    const int l15 = lane & 15;
    const int l4 = lane >> 4;

    const int row0 = by * 256;
    const int col0 = bx * 128;

    // staging sources with inverse chunk rotation
    const char* srcs[NU];
#pragma unroll
    for (int u = 0; u < NU; ++u) {
        int pl = u * T16 + t * 16;
        if (u < AU) {
            int lrow = pl >> 6;
            int c = (((pl >> 4) & 3) - ((lrow >> 1) & 3)) & 3;
            srcs[u] = Ab + (long)(row0 + lrow) * lda2 + c * 16;
        } else {
            int pb = pl - ABY;
            int lrow = pb >> 6;
            int c = (((pb >> 4) & 3) - ((lrow >> 1) & 3)) & 3;
            srcs[u] = Bb + (long)(col0 + lrow) * ldb2 + c * 16;
        }
    }
    const int ld16 = t * 16;

    auto STAGE = [&](int slot, long koff) {
        char* base = &lds[slot * SLOT];
#pragma unroll
        for (int u = 0; u < NU; ++u)
            gload_lds16(srcs[u] + koff, base + u * T16 + ld16);
    };
    auto KOFF = [](int p) { return (long)(p >> 1) * 128 + (long)(p & 1) * 64; };

    floatx4 acc[8][4] = {};
    const int nk = K / 64, np = 2 * nk;

    // prologue: stage phases 0..RING-2
#pragma unroll
    for (int r = 0; r < RING - 1; ++r) STAGE(r, KOFF(r));
    asm volatile("s_waitcnt vmcnt(%0)" :: "n"(VW) : "memory");
    GBAR();

    int slot = 0;
    for (int pp = 0; pp < np; ++pp) {
        const char* sb = &lds[slot * SLOT];
        bf16x8 af[8], bfr[4];
#pragma unroll
        for (int m = 0; m < 8; ++m) {
            int lr = wm * 128 + m * 16 + l15;
            int p = (l4 + ((lr >> 1) & 3)) & 3;
            af[m] = *(const bf16x8*)(sb + lr * 64 + p * 16);
        }
#pragma unroll
        for (int n = 0; n < 4; ++n) {
            int lr = wn * 64 + n * 16 + l15;
            int p = (l4 + ((lr >> 1) & 3)) & 3;
            bfr[n] = *(const bf16x8*)(sb + ABY + lr * 64 + p * 16);
        }

        const int pf = pp + RING - 1;
        int s2 = slot + RING - 1; if (s2 >= RING) s2 -= RING;
        if (pf < np) STAGE(s2, KOFF(pf));

        __builtin_amdgcn_s_setprio(1);
#pragma unroll
        for (int m = 0; m < 8; ++m)
#pragma unroll
            for (int n = 0; n < 4; ++n)
                acc[m][n] = MFMA(af[m], bfr[n], acc[m][n]);
        __builtin_amdgcn_s_setprio(0);

        asm volatile("s_waitcnt lgkmcnt(0)" ::: "memory");
        if (pf < np) asm volatile("s_waitcnt vmcnt(%0)" :: "n"(VW) : "memory");
        else         asm volatile("s_waitcnt vmcnt(0)" ::: "memory");
        GBAR();
        slot = (slot == RING - 1) ? 0 : slot + 1;
    }

    // ---- epilogue
    const int rq = l4 * 4;
    if constexpr (MODE == 0) {
        bf16* C = ((bf16*)Cout) + (long)z * sC;
#pragma unroll
        for (int m = 0; m < 8; ++m)
#pragma unroll
            for (int i = 0; i < 4; ++i) {
                long gr = row0 + wm * 128 + m * 16 + rq + i;
#pragma unroll
                for (int n = 0; n < 4; ++n) {
                    int gc = col0 + wn * 64 + n * 16 + l15;
                    C[gr * ldc + gc] = (bf16)(acc[m][n][i] * scale);
                }
            }
    } else {
        float* C = (float*)Cout + (long)z * sC;
        const float* R = resid + (long)z * sC;
#pragma unroll
        for (int m = 0; m < 8; ++m)
#pragma unroll
            for (int i = 0; i < 4; ++i) {
                long gr = row0 + wm * 128 + m * 16 + rq + i;
#pragma unroll
                for (int n = 0; n < 4; ++n) {
                    int gc = col0 + wn * 64 + n * 16 + l15;
                    C[gr * ldc + gc] = acc[m][n][i] + bias[gc] + R[gr * ldc + gc];
                }
            }
    }
}

// ---------------- transpose VWc (from yv cols 1024..2047): per batch (SEQ x 1024 @ld 2048) -> (1024 x SEQ) ----------------
__global__ void transpose_v(const bf16* __restrict__ yv, bf16* __restrict__ out) {
    __shared__ __attribute__((aligned(16))) bf16 tile[64][72];
    const int z = blockIdx.z;
    const bf16* ib = yv + (long)z * SEQ * 2048 + 1024;
    bf16* ob = out + (long)z * SEQ * HIDDEN;
    const int d0 = blockIdx.x * 64;
    const int s0 = blockIdx.y * 64;
    const int t = threadIdx.x;
    const int r = t >> 4;
    const int c = (t & 15) * 4;
#pragma unroll
    for (int i = 0; i < 4; ++i) {
        bf16x4 v = *(const bf16x4*)&ib[(long)(s0 + r + i * 16) * 2048 + d0 + c];
        *(bf16x4*)&tile[r + i * 16][c] = v;
    }
    __syncthreads();
#pragma unroll
    for (int i = 0; i < 4; ++i) {
        const int dr = r + i * 16;
        bf16x4 o;
#pragma unroll
        for (int j = 0; j < 4; ++j) o[j] = tile[c + j][dr];
        *(bf16x4*)&ob[(long)(d0 + dr) * SEQ + s0 + c] = o;
    }
}

// ---------------- row softmax, in-place on bf16 scores ----------------
__global__ void softmax_rows(bf16* __restrict__ S, const int* __restrict__ mask) {
    const int b = blockIdx.y;
    const int row = blockIdx.x;
    bf16* srow = S + ((long)b * SEQ + row) * SEQ;
    const int* mrow = mask + b * SEQ;
    const int t = threadIdx.x;

    bf16x8 sv = *(const bf16x8*)&srow[t * 8];
    int4 m0 = ((const int4*)mrow)[t * 2];
    int4 m1 = ((const int4*)mrow)[t * 2 + 1];
    int mk[8] = {m0.x, m0.y, m0.z, m0.w, m1.x, m1.y, m1.z, m1.w};

    float v[8];
    float mx = -1e30f;
#pragma unroll
    for (int j = 0; j < 8; ++j) {
        float s = (float)sv[j];
        if (mk[j] == 0) s = -1e9f;
        v[j] = s;
        mx = fmaxf(mx, s);
    }
    __shared__ float redm[4], reds[4];
#pragma unroll
    for (int off = 32; off > 0; off >>= 1) mx = fmaxf(mx, __shfl_down(mx, off));
    if ((t & 63) == 0) redm[t >> 6] = mx;
    __syncthreads();
    mx = fmaxf(fmaxf(redm[0], redm[1]), fmaxf(redm[2], redm[3]));

    float sum = 0.f;
#pragma unroll
    for (int j = 0; j < 8; ++j) {
        v[j] = __expf(v[j] - mx);
        sum += v[j];
    }
#pragma unroll
    for (int off = 32; off > 0; off >>= 1) sum += __shfl_down(sum, off);
    if ((t & 63) == 0) reds[t >> 6] = sum;
    __syncthreads();
    sum = reds[0] + reds[1] + reds[2] + reds[3];
    float inv = 1.0f / sum;

    bf16x8 o;
#pragma unroll
    for (int j = 0; j < 8; ++j) o[j] = (bf16)(v[j] * inv);
    *(bf16x8*)&srow[t * 8] = o;
}

// ---------------- LayerNorm: h (fp32) -> out (fp32) ----------------
__global__ void layernorm_out(const float* __restrict__ h, const float* __restrict__ gamma,
                              const float* __restrict__ beta, float* __restrict__ out) {
    const long row = blockIdx.x;
    const float* hr = h + row * HIDDEN;
    const int t = threadIdx.x;
    float4 v = ((const float4*)hr)[t];
    float s = v.x + v.y + v.z + v.w;
    float sq = v.x * v.x + v.y * v.y + v.z * v.z + v.w * v.w;
    __shared__ float rs[4], rq[4];
#pragma unroll
    for (int off = 32; off > 0; off >>= 1) {
        s += __shfl_down(s, off);
        sq += __shfl_down(sq, off);
    }
    if ((t & 63) == 0) { rs[t >> 6] = s; rq[t >> 6] = sq; }
    __syncthreads();
    s = rs[0] + rs[1] + rs[2] + rs[3];
    sq = rq[0] + rq[1] + rq[2] + rq[3];
    float mu = s * (1.0f / HIDDEN);
    float var = sq * (1.0f / HIDDEN) - mu * mu;
    float rinv = rsqrtf(var + LN_EPS);
    float4 g = ((const float4*)gamma)[t];
    float4 bt = ((const float4*)beta)[t];
    float4 o;
    o.x = (v.x - mu) * rinv * g.x + bt.x;
    o.y = (v.y - mu) * rinv * g.y + bt.y;
    o.z = (v.z - mu) * rinv * g.z + bt.z;
    o.w = (v.w - mu) * rinv * g.w + bt.w;
    ((float4*)(out + row * HIDDEN))[t] = o;
}

// ---------------- launch ----------------
extern "C" void kernel_launch(void* const* d_in, const int* in_sizes, int n_in,
                              void* d_out, int out_size, void* d_ws, size_t ws_size,
                              hipStream_t stream) {
    const float* x     = (const float*)d_in[0];
    const int*   mask  = (const int*)d_in[1];
    const float* Wq    = (const float*)d_in[2];
    const float* Wk    = (const float*)d_in[3];
    const float* Wv    = (const float*)d_in[4];
    const float* Wo    = (const float*)d_in[5];
    const float* bo    = (const float*)d_in[6];
    const float* gamma = (const float*)d_in[7];
    const float* beta  = (const float*)d_in[8];
    float* out = (float*)d_out;

    char* ws = (char*)d_ws;
    const long MB = 1024L * 1024L;
    bf16* yv   = (bf16*)(ws + 0 * MB);    // 32 MB (8192 x 2048) [y | VWc]
    float* h   = (float*)(ws + 0 * MB);   // 32 MB fp32, reuses yv after scores
    bf16* xb   = (bf16*)(ws + 32 * MB);   // 16 MB
    bf16* vt   = (bf16*)(ws + 48 * MB);   // 16 MB (per batch 1024 x 2048)
    bf16* wgc  = (bf16*)(ws + 64 * MB);   // 4 MB (2048 x 1024): [Gt ; Wc]
    bf16* wkT  = (bf16*)(ws + 68 * MB);   // 2 MB  -- A-block 0
    bf16* wo   = (bf16*)(ws + 70 * MB);   // 2 MB  -- A-block 1
    bf16* wqT  = (bf16*)(ws + 72 * MB);   // 2 MB  -- B-block 0
    bf16* wvT  = (bf16*)(ws + 74 * MB);   // 2 MB  -- B-block 1
    bf16* S    = (bf16*)(ws + 76 * MB);   // 32 MB scores/probs

    const int BS = BATCH * SEQ;  // 8192
    const int WW = HIDDEN * HIDDEN;
    dim3 blk256(256);

    // input + weight prep
    cvt_f32_bf16<<<dim3(BS * HIDDEN / 4 / 256), blk256, 0, stream>>>(x, xb, BS * HIDDEN / 4);
    cvt_f32_bf16<<<dim3(WW / 4 / 256), blk256, 0, stream>>>(Wo, wo, WW / 4);
    transpose_w3<<<dim3(16, 16, 3), blk256, 0, stream>>>(Wq, Wk, Wv, wqT, wkT, wvT);

    // [Gt ; Wc] in one z=2 launch:
    //   z=0: Gt = wkT * wqT^T  (Gt[j,d] = sum_f Wk[f,j] Wq[f,d])
    //   z=1: Wc = wo  * wvT^T  (Wc[i,j] = sum_d Wo[i,d] Wv[d,j])
    gemm_p<3, 0><<<dim3(HIDDEN / 128, HIDDEN / 256, 2), blk256, 0, stream>>>(
        wkT, wqT, wgc, nullptr, nullptr, HIDDEN, HIDDEN, HIDDEN, HIDDEN, 1.0f,
        (long)WW, (long)WW, (long)WW);

    // fused projection: yv = xb * wgc^T  (8192 x 2048)   [y = x*G | VWc = x*Wc^T]
    gemm_p<3, 0><<<dim3(2048 / 128, BS / 256, 1), blk256, 0, stream>>>(
        xb, wgc, yv, nullptr, nullptr, HIDDEN, HIDDEN, 2048, HIDDEN, 1.0f, 0, 0, 0);

    // VWc -> vt per batch
    transpose_v<<<dim3(HIDDEN / 64, SEQ / 64, BATCH), blk256, 0, stream>>>(yv, vt);

    // scores: per batch (2048x2048) = y * x^T * SCALE
    gemm_p<3, 0><<<dim3(SEQ / 128, SEQ / 256, BATCH), blk256, 0, stream>>>(
        yv, xb, S, nullptr, nullptr, 2048, HIDDEN, SEQ, HIDDEN, ATT_SCALE,
        (long)SEQ * 2048, (long)SEQ * HIDDEN, (long)SEQ * SEQ);

    softmax_rows<<<dim3(SEQ, BATCH), blk256, 0, stream>>>(S, mask);

    // h = P * vt^T + bo + x : per batch (2048x1024), K=2048, fp32 out
    gemm_p<4, 2><<<dim3(HIDDEN / 128, SEQ / 256, BATCH), blk256, 0, stream>>>(
        S, vt, h, bo, x, SEQ, SEQ, HIDDEN, SEQ, 1.0f,
        (long)SEQ * SEQ, (long)HIDDEN * SEQ, (long)SEQ * HIDDEN);

    layernorm_out<<<dim3(BS), blk256, 0, stream>>>(h, gamma, beta, out);
}

// Round 8
// 187.145 us; speedup vs baseline: 1.4657x; 1.0253x over previous
//
#include <hip/hip_runtime.h>

typedef __bf16 bf16;
typedef __bf16 bf16x8 __attribute__((ext_vector_type(8)));
typedef __bf16 bf16x4 __attribute__((ext_vector_type(4)));
typedef float floatx4 __attribute__((ext_vector_type(4)));

#define HIDDEN 1024
#define SEQ 2048
#define BATCH 4
#define ATT_SCALE 0.0625f
#define LN_EPS 1e-5f

__device__ __forceinline__ void gload_lds16(const void* g, void* l) {
    __builtin_amdgcn_global_load_lds(
        (const __attribute__((address_space(1))) unsigned int*)g,
        (__attribute__((address_space(3))) unsigned int*)l, 16, 0, 0);
}

#define GBAR() asm volatile("s_barrier" ::: "memory")
#define MFMA(a, b, c) __builtin_amdgcn_mfma_f32_16x16x32_bf16(a, b, c, 0, 0, 0)

// ---------------- fp32 -> bf16 conversion ----------------
__global__ void cvt_f32_bf16(const float* __restrict__ in, bf16* __restrict__ out, int n4) {
    int i = blockIdx.x * blockDim.x + threadIdx.x;
    if (i >= n4) return;
    float4 v = ((const float4*)in)[i];
    bf16x4 o;
    o[0] = (bf16)v.x; o[1] = (bf16)v.y; o[2] = (bf16)v.z; o[3] = (bf16)v.w;
    ((bf16x4*)out)[i] = o;
}

// ---------------- transpose 3 weight matrices (fp32 1024x1024 -> bf16 transposed) ----------------
__global__ void transpose_w3(const float* __restrict__ s0, const float* __restrict__ s1,
                             const float* __restrict__ s2,
                             bf16* __restrict__ d0p, bf16* __restrict__ d1p, bf16* __restrict__ d2p) {
    const float* in = (blockIdx.z == 0) ? s0 : (blockIdx.z == 1) ? s1 : s2;
    bf16* out = (blockIdx.z == 0) ? d0p : (blockIdx.z == 1) ? d1p : d2p;
    __shared__ __attribute__((aligned(16))) bf16 tile[64][72];
    const int d0 = blockIdx.x * 64;
    const int f0 = blockIdx.y * 64;
    const int t = threadIdx.x;
    const int r = t >> 4;
    const int c = (t & 15) * 4;
#pragma unroll
    for (int i = 0; i < 4; ++i) {
        float4 v = *(const float4*)&in[(long)(f0 + r + i * 16) * HIDDEN + d0 + c];
        bf16x4 b;
        b[0] = (bf16)v.x; b[1] = (bf16)v.y; b[2] = (bf16)v.z; b[3] = (bf16)v.w;
        *(bf16x4*)&tile[r + i * 16][c] = b;
    }
    __syncthreads();
#pragma unroll
    for (int i = 0; i < 4; ++i) {
        const int dr = r + i * 16;
        bf16x4 o;
#pragma unroll
        for (int j = 0; j < 4; ++j) o[j] = tile[c + j][dr];
        *(bf16x4*)&out[(long)(d0 + dr) * HIDDEN + f0 + c] = o;
    }
}

// ---------------- GEMM: C = A (MxK) * B^T (B is NxK), bf16 inputs ----------------
// 512 threads = 8 waves. BM=256 fixed. BNv=256: 2Mx4N waves, wave tile 128x64;
// BNv=128: 4Mx2N waves, wave tile 64x64. BK=64 (128B rows). 2-slot LDS dbuf.
// Stage ALL of tile t+1 in one burst at phase 0 of tile t; single vmcnt(0) at
// tile end (issue->deadline ~3 phases >> HBM latency). 16-MFMA sub-phases with
// 2 barriers each, setprio(1) around MFMA. Rows stored with 16B-chunk rotation
// chunk' = (chunk + row) & 7 -> conflict-free ds_read_b128; global_load_lds
// dest linear, source carries inverse rotation (both-sides rule).
// MODE 0: bf16 C = acc*scale ; MODE 2: fp32 C = acc + bias[col] + resid (z-offset)
template <int BNv, int MODE>
__global__ __launch_bounds__(512, 2)
void gemm256(const bf16* A, const bf16* Bw, void* __restrict__ Cout,
             const float* __restrict__ bias, const float* __restrict__ resid,
             int lda, int ldb, int ldc, int K, float scale,
             long sA, long sB, long sC) {
    constexpr int ABY = 256 * 128;          // 32 KB A-tile
    constexpr int BBY = BNv * 128;          // 32/16 KB B-tile
    constexpr int SLOT = ABY + BBY;
    constexpr int AU = ABY / 8192;          // 4 gload units A
    constexpr int BU = BBY / 8192;          // 4 or 2 units B
    constexpr int WMc = (BNv == 256) ? 2 : 4;
    constexpr int WNc = (BNv == 256) ? 4 : 2;
    constexpr int MR = (BNv == 256) ? 8 : 4;    // m-frags per wave
    constexpr int MH = MR / 2;

    __shared__ __attribute__((aligned(16))) char lds[2 * SLOT];

    // XCD-aware block swizzle (all grids have nb % 8 == 0)
    const int gx = gridDim.x;
    const int nblk = gx * gridDim.y;
    const int bid = blockIdx.y * gx + blockIdx.x;
    const int cpx = nblk >> 3;
    const int sbid = (nblk & 7) ? bid : (bid & 7) * cpx + (bid >> 3);
    const int bx = sbid % gx, by = sbid / gx;

    const int z = blockIdx.z;
    const char* Ab = (const char*)(A + (long)z * sA);
    const char* Bb = (const char*)(Bw + (long)z * sB);
    const long lda2 = lda * 2L, ldb2 = ldb * 2L;

    const int t = threadIdx.x;
    const int lane = t & 63;
    const int w = t >> 6;
    const int wm = w / WNc, wn = w % WNc;
    const int l15 = lane & 15;
    const int l4 = lane >> 4;

    const int row0 = by * 256;
    const int col0 = bx * BNv;

    // staging source bases (inverse chunk rotation; unit offsets are uniform)
    const int srow = t >> 3;                        // local row within unit
    const int soff = (((t & 7) - (srow & 7)) & 7) * 16;
    const char* aP = Ab + (long)(row0 + srow) * lda2 + soff;
    const char* bP = Bb + (long)(col0 + srow) * ldb2 + soff;
    const int ld16 = t * 16;

    auto STAGE = [&](int slot, long koff) {
        char* base = &lds[slot * SLOT];
#pragma unroll
        for (int u = 0; u < AU; ++u)
            gload_lds16(aP + u * 64 * lda2 + koff, base + u * 8192 + ld16);
#pragma unroll
        for (int u = 0; u < BU; ++u)
            gload_lds16(bP + u * 64 * ldb2 + koff, base + ABY + u * 8192 + ld16);
    };

    floatx4 acc[MR][4] = {};
    const int nk = K / 64;

    // prologue: tile 0 -> slot 0
    STAGE(0, 0);
    asm volatile("s_waitcnt vmcnt(0)" ::: "memory");
    GBAR();

    for (int tt = 0; tt < nk; ++tt) {
        const char* sb = &lds[(tt & 1) * SLOT];
        const int ns = (tt + 1) & 1;

        bf16x8 af[MH][2], b0[2][2], b1[2][2];

        auto RDA = [&](int m, int kkh) {
            int lr = wm * (MR * 16) + m * 16 + l15;
            return *(const bf16x8*)(sb + lr * 128 + (((kkh * 4 + l4 + lr) & 7) << 4));
        };
        auto RDB = [&](int n, int kkh) {
            int lr = wn * 64 + n * 16 + l15;
            return *(const bf16x8*)(sb + ABY + lr * 128 + (((kkh * 4 + l4 + lr) & 7) << 4));
        };

        // ---- phase 0: read af(m0..MH-1) + b(n0,n1); stage whole tile t+1
#pragma unroll
        for (int m = 0; m < MH; ++m) { af[m][0] = RDA(m, 0); af[m][1] = RDA(m, 1); }
#pragma unroll
        for (int n = 0; n < 2; ++n) { b0[n][0] = RDB(n, 0); b0[n][1] = RDB(n, 1); }
        if (tt + 1 < nk) STAGE(ns, (long)(tt + 1) * 128);
        GBAR();
        asm volatile("s_waitcnt lgkmcnt(0)" ::: "memory");
        __builtin_amdgcn_s_setprio(1);
#pragma unroll
        for (int m = 0; m < MH; ++m)
#pragma unroll
            for (int n = 0; n < 2; ++n) {
                acc[m][n] = MFMA(af[m][0], b0[n][0], acc[m][n]);
                acc[m][n] = MFMA(af[m][1], b0[n][1], acc[m][n]);
            }
        __builtin_amdgcn_s_setprio(0);
        GBAR();

        // ---- phase 1: read b(n2,n3); MFMA af x b1
#pragma unroll
        for (int n = 0; n < 2; ++n) { b1[n][0] = RDB(2 + n, 0); b1[n][1] = RDB(2 + n, 1); }
        GBAR();
        asm volatile("s_waitcnt lgkmcnt(0)" ::: "memory");
        __builtin_amdgcn_s_setprio(1);
#pragma unroll
        for (int m = 0; m < MH; ++m)
#pragma unroll
            for (int n = 0; n < 2; ++n) {
                acc[m][2 + n] = MFMA(af[m][0], b1[n][0], acc[m][2 + n]);
                acc[m][2 + n] = MFMA(af[m][1], b1[n][1], acc[m][2 + n]);
            }
        __builtin_amdgcn_s_setprio(0);

        if constexpr (BNv == 256) {
            GBAR();
            // ---- phase 2: read af(m4..7) (reuse af storage); MFMA x b0
#pragma unroll
            for (int m = 0; m < MH; ++m) { af[m][0] = RDA(MH + m, 0); af[m][1] = RDA(MH + m, 1); }
            GBAR();
            asm volatile("s_waitcnt lgkmcnt(0)" ::: "memory");
            __builtin_amdgcn_s_setprio(1);
#pragma unroll
            for (int m = 0; m < MH; ++m)
#pragma unroll
                for (int n = 0; n < 2; ++n) {
                    acc[MH + m][n] = MFMA(af[m][0], b0[n][0], acc[MH + m][n]);
                    acc[MH + m][n] = MFMA(af[m][1], b0[n][1], acc[MH + m][n]);
                }
            __builtin_amdgcn_s_setprio(0);
            GBAR();

            // ---- phase 3: MFMA af(m4..7) x b1 (no reads)
            __builtin_amdgcn_s_setprio(1);
#pragma unroll
            for (int m = 0; m < MH; ++m)
#pragma unroll
                for (int n = 0; n < 2; ++n) {
                    acc[MH + m][2 + n] = MFMA(af[m][0], b1[n][0], acc[MH + m][2 + n]);
                    acc[MH + m][2 + n] = MFMA(af[m][1], b1[n][1], acc[MH + m][2 + n]);
                }
            __builtin_amdgcn_s_setprio(0);
        }

        asm volatile("s_waitcnt vmcnt(0)" ::: "memory");
        GBAR();
    }

    // ---- epilogue
    const int rq = l4 * 4;
    if constexpr (MODE == 0) {
        bf16* C = ((bf16*)Cout) + (long)z * sC;
#pragma unroll
        for (int m = 0; m < MR; ++m)
#pragma unroll
            for (int i = 0; i < 4; ++i) {
                long gr = row0 + wm * (MR * 16) + m * 16 + rq + i;
#pragma unroll
                for (int n = 0; n < 4; ++n) {
                    int gc = col0 + wn * 64 + n * 16 + l15;
                    C[gr * ldc + gc] = (bf16)(acc[m][n][i] * scale);
                }
            }
    } else {
        float* C = (float*)Cout + (long)z * sC;
        const float* R = resid + (long)z * sC;
#pragma unroll
        for (int m = 0; m < MR; ++m)
#pragma unroll
            for (int i = 0; i < 4; ++i) {
                long gr = row0 + wm * (MR * 16) + m * 16 + rq + i;
#pragma unroll
                for (int n = 0; n < 4; ++n) {
                    int gc = col0 + wn * 64 + n * 16 + l15;
                    C[gr * ldc + gc] = acc[m][n][i] + bias[gc] + R[gr * ldc + gc];
                }
            }
    }
}

// ---------------- transpose VWc (from yv cols 1024..2047): per batch (SEQ x 1024 @ld 2048) -> (1024 x SEQ) ----------------
__global__ void transpose_v(const bf16* __restrict__ yv, bf16* __restrict__ out) {
    __shared__ __attribute__((aligned(16))) bf16 tile[64][72];
    const int z = blockIdx.z;
    const bf16* ib = yv + (long)z * SEQ * 2048 + 1024;
    bf16* ob = out + (long)z * SEQ * HIDDEN;
    const int d0 = blockIdx.x * 64;
    const int s0 = blockIdx.y * 64;
    const int t = threadIdx.x;
    const int r = t >> 4;
    const int c = (t & 15) * 4;
#pragma unroll
    for (int i = 0; i < 4; ++i) {
        bf16x4 v = *(const bf16x4*)&ib[(long)(s0 + r + i * 16) * 2048 + d0 + c];
        *(bf16x4*)&tile[r + i * 16][c] = v;
    }
    __syncthreads();
#pragma unroll
    for (int i = 0; i < 4; ++i) {
        const int dr = r + i * 16;
        bf16x4 o;
#pragma unroll
        for (int j = 0; j < 4; ++j) o[j] = tile[c + j][dr];
        *(bf16x4*)&ob[(long)(d0 + dr) * SEQ + s0 + c] = o;
    }
}

// ---------------- row softmax, in-place on bf16 scores ----------------
__global__ void softmax_rows(bf16* __restrict__ S, const int* __restrict__ mask) {
    const int b = blockIdx.y;
    const int row = blockIdx.x;
    bf16* srow = S + ((long)b * SEQ + row) * SEQ;
    const int* mrow = mask + b * SEQ;
    const int t = threadIdx.x;

    bf16x8 sv = *(const bf16x8*)&srow[t * 8];
    int4 m0 = ((const int4*)mrow)[t * 2];
    int4 m1 = ((const int4*)mrow)[t * 2 + 1];
    int mk[8] = {m0.x, m0.y, m0.z, m0.w, m1.x, m1.y, m1.z, m1.w};

    float v[8];
    float mx = -1e30f;
#pragma unroll
    for (int j = 0; j < 8; ++j) {
        float s = (float)sv[j];
        if (mk[j] == 0) s = -1e9f;
        v[j] = s;
        mx = fmaxf(mx, s);
    }
    __shared__ float redm[4], reds[4];
#pragma unroll
    for (int off = 32; off > 0; off >>= 1) mx = fmaxf(mx, __shfl_down(mx, off));
    if ((t & 63) == 0) redm[t >> 6] = mx;
    __syncthreads();
    mx = fmaxf(fmaxf(redm[0], redm[1]), fmaxf(redm[2], redm[3]));

    float sum = 0.f;
#pragma unroll
    for (int j = 0; j < 8; ++j) {
        v[j] = __expf(v[j] - mx);
        sum += v[j];
    }
#pragma unroll
    for (int off = 32; off > 0; off >>= 1) sum += __shfl_down(sum, off);
    if ((t & 63) == 0) reds[t >> 6] = sum;
    __syncthreads();
    sum = reds[0] + reds[1] + reds[2] + reds[3];
    float inv = 1.0f / sum;

    bf16x8 o;
#pragma unroll
    for (int j = 0; j < 8; ++j) o[j] = (bf16)(v[j] * inv);
    *(bf16x8*)&srow[t * 8] = o;
}

// ---------------- LayerNorm: h (fp32) -> out (fp32) ----------------
__global__ void layernorm_out(const float* __restrict__ h, const float* __restrict__ gamma,
                              const float* __restrict__ beta, float* __restrict__ out) {
    const long row = blockIdx.x;
    const float* hr = h + row * HIDDEN;
    const int t = threadIdx.x;
    float4 v = ((const float4*)hr)[t];
    float s = v.x + v.y + v.z + v.w;
    float sq = v.x * v.x + v.y * v.y + v.z * v.z + v.w * v.w;
    __shared__ float rs[4], rq[4];
#pragma unroll
    for (int off = 32; off > 0; off >>= 1) {
        s += __shfl_down(s, off);
        sq += __shfl_down(sq, off);
    }
    if ((t & 63) == 0) { rs[t >> 6] = s; rq[t >> 6] = sq; }
    __syncthreads();
    s = rs[0] + rs[1] + rs[2] + rs[3];
    sq = rq[0] + rq[1] + rq[2] + rq[3];
    float mu = s * (1.0f / HIDDEN);
    float var = sq * (1.0f / HIDDEN) - mu * mu;
    float rinv = rsqrtf(var + LN_EPS);
    float4 g = ((const float4*)gamma)[t];
    float4 bt = ((const float4*)beta)[t];
    float4 o;
    o.x = (v.x - mu) * rinv * g.x + bt.x;
    o.y = (v.y - mu) * rinv * g.y + bt.y;
    o.z = (v.z - mu) * rinv * g.z + bt.z;
    o.w = (v.w - mu) * rinv * g.w + bt.w;
    ((float4*)(out + row * HIDDEN))[t] = o;
}

// ---------------- launch ----------------
extern "C" void kernel_launch(void* const* d_in, const int* in_sizes, int n_in,
                              void* d_out, int out_size, void* d_ws, size_t ws_size,
                              hipStream_t stream) {
    const float* x     = (const float*)d_in[0];
    const int*   mask  = (const int*)d_in[1];
    const float* Wq    = (const float*)d_in[2];
    const float* Wk    = (const float*)d_in[3];
    const float* Wv    = (const float*)d_in[4];
    const float* Wo    = (const float*)d_in[5];
    const float* bo    = (const float*)d_in[6];
    const float* gamma = (const float*)d_in[7];
    const float* beta  = (const float*)d_in[8];
    float* out = (float*)d_out;

    char* ws = (char*)d_ws;
    const long MB = 1024L * 1024L;
    bf16* yv   = (bf16*)(ws + 0 * MB);    // 32 MB (8192 x 2048) [y | VWc]
    float* h   = (float*)(ws + 0 * MB);   // 32 MB fp32, reuses yv after scores
    bf16* xb   = (bf16*)(ws + 32 * MB);   // 16 MB
    bf16* vt   = (bf16*)(ws + 48 * MB);   // 16 MB (per batch 1024 x 2048)
    bf16* wgc  = (bf16*)(ws + 64 * MB);   // 4 MB (2048 x 1024): [Gt ; Wc]
    bf16* wkT  = (bf16*)(ws + 68 * MB);   // 2 MB  -- A-block 0
    bf16* wo   = (bf16*)(ws + 70 * MB);   // 2 MB  -- A-block 1
    bf16* wqT  = (bf16*)(ws + 72 * MB);   // 2 MB  -- B-block 0
    bf16* wvT  = (bf16*)(ws + 74 * MB);   // 2 MB  -- B-block 1
    bf16* S    = (bf16*)(ws + 76 * MB);   // 32 MB scores/probs

    const int BS = BATCH * SEQ;  // 8192
    const int WW = HIDDEN * HIDDEN;
    dim3 blk256(256), blk512(512);

    // input + weight prep
    cvt_f32_bf16<<<dim3(BS * HIDDEN / 4 / 256), blk256, 0, stream>>>(x, xb, BS * HIDDEN / 4);
    cvt_f32_bf16<<<dim3(WW / 4 / 256), blk256, 0, stream>>>(Wo, wo, WW / 4);
    transpose_w3<<<dim3(16, 16, 3), blk256, 0, stream>>>(Wq, Wk, Wv, wqT, wkT, wvT);

    // [Gt ; Wc] in one z=2 launch (2048x1024, K=1024):
    //   z=0: Gt = wkT * wqT^T ; z=1: Wc = wo * wvT^T
    gemm256<128, 0><<<dim3(HIDDEN / 128, 2048 / 256, 2), blk512, 0, stream>>>(
        wkT, wqT, wgc, nullptr, nullptr, HIDDEN, HIDDEN, HIDDEN, HIDDEN, 1.0f,
        (long)WW, (long)WW, (long)WW);

    // fused projection: yv = xb * wgc^T  (8192 x 2048)  [y = x*G | VWc]  grid 8x32 = 256
    gemm256<256, 0><<<dim3(2048 / 256, BS / 256, 1), blk512, 0, stream>>>(
        xb, wgc, yv, nullptr, nullptr, HIDDEN, HIDDEN, 2048, HIDDEN, 1.0f, 0, 0, 0);

    // VWc -> vt per batch
    transpose_v<<<dim3(HIDDEN / 64, SEQ / 64, BATCH), blk256, 0, stream>>>(yv, vt);

    // scores: per batch (2048x2048) = y * x^T * SCALE  grid 8x8x4 = 256
    gemm256<256, 0><<<dim3(SEQ / 256, SEQ / 256, BATCH), blk512, 0, stream>>>(
        yv, xb, S, nullptr, nullptr, 2048, HIDDEN, SEQ, HIDDEN, ATT_SCALE,
        (long)SEQ * 2048, (long)SEQ * HIDDEN, (long)SEQ * SEQ);

    softmax_rows<<<dim3(SEQ, BATCH), blk256, 0, stream>>>(S, mask);

    // h = P * vt^T + bo + x : per batch (2048x1024), K=2048, fp32 out  grid 8x8x4 = 256
    gemm256<128, 2><<<dim3(HIDDEN / 128, SEQ / 256, BATCH), blk512, 0, stream>>>(
        S, vt, h, bo, x, SEQ, SEQ, HIDDEN, SEQ, 1.0f,
        (long)SEQ * SEQ, (long)HIDDEN * SEQ, (long)SEQ * HIDDEN);

    layernorm_out<<<dim3(BS), blk256, 0, stream>>>(h, gamma, beta, out);
}

// Round 9
// 181.337 us; speedup vs baseline: 1.5127x; 1.0320x over previous
//
#include <hip/hip_runtime.h>

typedef __bf16 bf16;
typedef __bf16 bf16x8 __attribute__((ext_vector_type(8)));
typedef __bf16 bf16x4 __attribute__((ext_vector_type(4)));
typedef float floatx4 __attribute__((ext_vector_type(4)));

#define HIDDEN 1024
#define SEQ 2048
#define BATCH 4
#define ATT_SCALE 0.0625f
#define LN_EPS 1e-5f

__device__ __forceinline__ void gload_lds16(const void* g, void* l) {
    __builtin_amdgcn_global_load_lds(
        (const __attribute__((address_space(1))) unsigned int*)g,
        (__attribute__((address_space(3))) unsigned int*)l, 16, 0, 0);
}

#define GBAR() asm volatile("s_barrier" ::: "memory")
#define MFMA(a, b, c) __builtin_amdgcn_mfma_f32_16x16x32_bf16(a, b, c, 0, 0, 0)

// ---------------- fp32 -> bf16 conversion ----------------
__global__ void cvt_f32_bf16(const float* __restrict__ in, bf16* __restrict__ out, int n4) {
    int i = blockIdx.x * blockDim.x + threadIdx.x;
    if (i >= n4) return;
    float4 v = ((const float4*)in)[i];
    bf16x4 o;
    o[0] = (bf16)v.x; o[1] = (bf16)v.y; o[2] = (bf16)v.z; o[3] = (bf16)v.w;
    ((bf16x4*)out)[i] = o;
}

// ---------------- transpose 3 weight matrices (fp32 1024x1024 -> bf16 transposed) ----------------
__global__ void transpose_w3(const float* __restrict__ s0, const float* __restrict__ s1,
                             const float* __restrict__ s2,
                             bf16* __restrict__ d0p, bf16* __restrict__ d1p, bf16* __restrict__ d2p) {
    const float* in = (blockIdx.z == 0) ? s0 : (blockIdx.z == 1) ? s1 : s2;
    bf16* out = (blockIdx.z == 0) ? d0p : (blockIdx.z == 1) ? d1p : d2p;
    __shared__ __attribute__((aligned(16))) bf16 tile[64][72];
    const int d0 = blockIdx.x * 64;
    const int f0 = blockIdx.y * 64;
    const int t = threadIdx.x;
    const int r = t >> 4;
    const int c = (t & 15) * 4;
#pragma unroll
    for (int i = 0; i < 4; ++i) {
        float4 v = *(const float4*)&in[(long)(f0 + r + i * 16) * HIDDEN + d0 + c];
        bf16x4 b;
        b[0] = (bf16)v.x; b[1] = (bf16)v.y; b[2] = (bf16)v.z; b[3] = (bf16)v.w;
        *(bf16x4*)&tile[r + i * 16][c] = b;
    }
    __syncthreads();
#pragma unroll
    for (int i = 0; i < 4; ++i) {
        const int dr = r + i * 16;
        bf16x4 o;
#pragma unroll
        for (int j = 0; j < 4; ++j) o[j] = tile[c + j][dr];
        *(bf16x4*)&out[(long)(d0 + dr) * HIDDEN + f0 + c] = o;
    }
}

// ---------------- GEMM: C = A (MxK) * B^T (B is NxK), bf16 inputs ----------------
// 512 threads = 8 waves. BM=256. BNv=256: 2Mx4N waves, wave tile 128x64;
// BNv=128: 4Mx2N waves, wave tile 64x64. BK=64 (128B rows). 2-slot LDS dbuf.
// One barrier + one vmcnt(0) per K-tile: issue all fragment ds_reads up front,
// burst-stage tile t+1, MFMA clusters behind compiler's counted lgkm waits
// (reads of later clusters overlap earlier MFMA). Safety: a wave passes the
// end-of-tile barrier only after its last MFMA consumed all its reads, so the
// next STAGE into the just-read slot cannot race; vmcnt(0)+barrier validates
// the prefetched slot. Rows stored with 16B-chunk rotation chunk'=(chunk+row)&7
// -> conflict-free ds_read_b128 (measured 0); gload_lds dest linear, source
// carries inverse rotation (both-sides rule).
// MODE 0: bf16 C = acc*scale ; MODE 2: fp32 C = acc + bias[col] + resid (z-offset)
template <int BNv, int MODE>
__global__ __launch_bounds__(512, 2)
void gemm256(const bf16* A, const bf16* Bw, void* __restrict__ Cout,
             const float* __restrict__ bias, const float* __restrict__ resid,
             int lda, int ldb, int ldc, int K, float scale,
             long sA, long sB, long sC) {
    constexpr int ABY = 256 * 128;          // 32 KB A-tile
    constexpr int BBY = BNv * 128;          // 32/16 KB B-tile
    constexpr int SLOT = ABY + BBY;
    constexpr int AU = ABY / 8192;          // 4 gload units A
    constexpr int BU = BBY / 8192;          // 4 or 2 units B
    constexpr int WNc = (BNv == 256) ? 4 : 2;
    constexpr int MR = (BNv == 256) ? 8 : 4;    // m-frags per wave
    constexpr int MH = MR / 2;

    __shared__ __attribute__((aligned(16))) char lds[2 * SLOT];

    // XCD-aware block swizzle (all grids have nb % 8 == 0)
    const int gx = gridDim.x;
    const int nblk = gx * gridDim.y;
    const int bid = blockIdx.y * gx + blockIdx.x;
    const int cpx = nblk >> 3;
    const int sbid = (nblk & 7) ? bid : (bid & 7) * cpx + (bid >> 3);
    const int bx = sbid % gx, by = sbid / gx;

    const int z = blockIdx.z;
    const char* Ab = (const char*)(A + (long)z * sA);
    const char* Bb = (const char*)(Bw + (long)z * sB);
    const long lda2 = lda * 2L, ldb2 = ldb * 2L;

    const int t = threadIdx.x;
    const int lane = t & 63;
    const int w = t >> 6;
    const int wm = w / WNc, wn = w % WNc;
    const int l15 = lane & 15;
    const int l4 = lane >> 4;

    const int row0 = by * 256;
    const int col0 = bx * BNv;

    // staging source bases (inverse chunk rotation; unit offsets are uniform)
    const int srow = t >> 3;                        // local row within unit
    const int soff = (((t & 7) - (srow & 7)) & 7) * 16;
    const char* aP = Ab + (long)(row0 + srow) * lda2 + soff;
    const char* bP = Bb + (long)(col0 + srow) * ldb2 + soff;
    const int ld16 = t * 16;

    auto STAGE = [&](int slot, long koff) {
        char* base = &lds[slot * SLOT];
#pragma unroll
        for (int u = 0; u < AU; ++u)
            gload_lds16(aP + u * 64 * lda2 + koff, base + u * 8192 + ld16);
#pragma unroll
        for (int u = 0; u < BU; ++u)
            gload_lds16(bP + u * 64 * ldb2 + koff, base + ABY + u * 8192 + ld16);
    };

    floatx4 acc[MR][4] = {};
    const int nk = K / 64;

    // prologue: tile 0 -> slot 0
    STAGE(0, 0);
    asm volatile("s_waitcnt vmcnt(0)" ::: "memory");
    GBAR();

    for (int tt = 0; tt < nk; ++tt) {
        const char* sb = &lds[(tt & 1) * SLOT];

        auto RDA = [&](int m, int kkh) {
            int lr = wm * (MR * 16) + m * 16 + l15;
            return *(const bf16x8*)(sb + lr * 128 + (((kkh * 4 + l4 + lr) & 7) << 4));
        };
        auto RDB = [&](int n, int kkh) {
            int lr = wn * 64 + n * 16 + l15;
            return *(const bf16x8*)(sb + ABY + lr * 128 + (((kkh * 4 + l4 + lr) & 7) << 4));
        };

        bf16x8 alo[MH][2], ahi[MH][2], b0[2][2], b1[2][2];
#pragma unroll
        for (int m = 0; m < MH; ++m) { alo[m][0] = RDA(m, 0); alo[m][1] = RDA(m, 1); }
#pragma unroll
        for (int n = 0; n < 2; ++n) {
            b0[n][0] = RDB(n, 0); b0[n][1] = RDB(n, 1);
            b1[n][0] = RDB(2 + n, 0); b1[n][1] = RDB(2 + n, 1);
        }

        if (tt + 1 < nk) STAGE((tt + 1) & 1, (long)(tt + 1) * 128);

        // cluster 0: alo x b0
        __builtin_amdgcn_s_setprio(1);
#pragma unroll
        for (int m = 0; m < MH; ++m)
#pragma unroll
            for (int n = 0; n < 2; ++n) {
                acc[m][n] = MFMA(alo[m][0], b0[n][0], acc[m][n]);
                acc[m][n] = MFMA(alo[m][1], b0[n][1], acc[m][n]);
            }
        __builtin_amdgcn_s_setprio(0);

        // hi A frags (overlap with cluster 1 via compiler counted waits)
#pragma unroll
        for (int m = 0; m < MH; ++m) { ahi[m][0] = RDA(MH + m, 0); ahi[m][1] = RDA(MH + m, 1); }

        // cluster 1: alo x b1
        __builtin_amdgcn_s_setprio(1);
#pragma unroll
        for (int m = 0; m < MH; ++m)
#pragma unroll
            for (int n = 0; n < 2; ++n) {
                acc[m][2 + n] = MFMA(alo[m][0], b1[n][0], acc[m][2 + n]);
                acc[m][2 + n] = MFMA(alo[m][1], b1[n][1], acc[m][2 + n]);
            }
        // clusters 2,3: ahi x b0, ahi x b1
#pragma unroll
        for (int m = 0; m < MH; ++m)
#pragma unroll
            for (int n = 0; n < 2; ++n) {
                acc[MH + m][n] = MFMA(ahi[m][0], b0[n][0], acc[MH + m][n]);
                acc[MH + m][n] = MFMA(ahi[m][1], b0[n][1], acc[MH + m][n]);
            }
#pragma unroll
        for (int m = 0; m < MH; ++m)
#pragma unroll
            for (int n = 0; n < 2; ++n) {
                acc[MH + m][2 + n] = MFMA(ahi[m][0], b1[n][0], acc[MH + m][2 + n]);
                acc[MH + m][2 + n] = MFMA(ahi[m][1], b1[n][1], acc[MH + m][2 + n]);
            }
        __builtin_amdgcn_s_setprio(0);

        asm volatile("s_waitcnt vmcnt(0)" ::: "memory");
        GBAR();
    }

    // ---- epilogue
    const int rq = l4 * 4;
    if constexpr (MODE == 0) {
        bf16* C = ((bf16*)Cout) + (long)z * sC;
#pragma unroll
        for (int m = 0; m < MR; ++m)
#pragma unroll
            for (int i = 0; i < 4; ++i) {
                long gr = row0 + wm * (MR * 16) + m * 16 + rq + i;
#pragma unroll
                for (int n = 0; n < 4; ++n) {
                    int gc = col0 + wn * 64 + n * 16 + l15;
                    C[gr * ldc + gc] = (bf16)(acc[m][n][i] * scale);
                }
            }
    } else {
        float* C = (float*)Cout + (long)z * sC;
        const float* R = resid + (long)z * sC;
#pragma unroll
        for (int m = 0; m < MR; ++m)
#pragma unroll
            for (int i = 0; i < 4; ++i) {
                long gr = row0 + wm * (MR * 16) + m * 16 + rq + i;
#pragma unroll
                for (int n = 0; n < 4; ++n) {
                    int gc = col0 + wn * 64 + n * 16 + l15;
                    C[gr * ldc + gc] = acc[m][n][i] + bias[gc] + R[gr * ldc + gc];
                }
            }
    }
}

// ---------------- transpose VWc (from yv cols 1024..2047): per batch (SEQ x 1024 @ld 2048) -> (1024 x SEQ) ----------------
__global__ void transpose_v(const bf16* __restrict__ yv, bf16* __restrict__ out) {
    __shared__ __attribute__((aligned(16))) bf16 tile[64][72];
    const int z = blockIdx.z;
    const bf16* ib = yv + (long)z * SEQ * 2048 + 1024;
    bf16* ob = out + (long)z * SEQ * HIDDEN;
    const int d0 = blockIdx.x * 64;
    const int s0 = blockIdx.y * 64;
    const int t = threadIdx.x;
    const int r = t >> 4;
    const int c = (t & 15) * 4;
#pragma unroll
    for (int i = 0; i < 4; ++i) {
        bf16x4 v = *(const bf16x4*)&ib[(long)(s0 + r + i * 16) * 2048 + d0 + c];
        *(bf16x4*)&tile[r + i * 16][c] = v;
    }
    __syncthreads();
#pragma unroll
    for (int i = 0; i < 4; ++i) {
        const int dr = r + i * 16;
        bf16x4 o;
#pragma unroll
        for (int j = 0; j < 4; ++j) o[j] = tile[c + j][dr];
        *(bf16x4*)&ob[(long)(d0 + dr) * SEQ + s0 + c] = o;
    }
}

// ---------------- row softmax, in-place on bf16 scores ----------------
__global__ void softmax_rows(bf16* __restrict__ S, const int* __restrict__ mask) {
    const int b = blockIdx.y;
    const int row = blockIdx.x;
    bf16* srow = S + ((long)b * SEQ + row) * SEQ;
    const int* mrow = mask + b * SEQ;
    const int t = threadIdx.x;

    bf16x8 sv = *(const bf16x8*)&srow[t * 8];
    int4 m0 = ((const int4*)mrow)[t * 2];
    int4 m1 = ((const int4*)mrow)[t * 2 + 1];
    int mk[8] = {m0.x, m0.y, m0.z, m0.w, m1.x, m1.y, m1.z, m1.w};

    float v[8];
    float mx = -1e30f;
#pragma unroll
    for (int j = 0; j < 8; ++j) {
        float s = (float)sv[j];
        if (mk[j] == 0) s = -1e9f;
        v[j] = s;
        mx = fmaxf(mx, s);
    }
    __shared__ float redm[4], reds[4];
#pragma unroll
    for (int off = 32; off > 0; off >>= 1) mx = fmaxf(mx, __shfl_down(mx, off));
    if ((t & 63) == 0) redm[t >> 6] = mx;
    __syncthreads();
    mx = fmaxf(fmaxf(redm[0], redm[1]), fmaxf(redm[2], redm[3]));

    float sum = 0.f;
#pragma unroll
    for (int j = 0; j < 8; ++j) {
        v[j] = __expf(v[j] - mx);
        sum += v[j];
    }
#pragma unroll
    for (int off = 32; off > 0; off >>= 1) sum += __shfl_down(sum, off);
    if ((t & 63) == 0) reds[t >> 6] = sum;
    __syncthreads();
    sum = reds[0] + reds[1] + reds[2] + reds[3];
    float inv = 1.0f / sum;

    bf16x8 o;
#pragma unroll
    for (int j = 0; j < 8; ++j) o[j] = (bf16)(v[j] * inv);
    *(bf16x8*)&srow[t * 8] = o;
}

// ---------------- LayerNorm: h (fp32) -> out (fp32) ----------------
__global__ void layernorm_out(const float* __restrict__ h, const float* __restrict__ gamma,
                              const float* __restrict__ beta, float* __restrict__ out) {
    const long row = blockIdx.x;
    const float* hr = h + row * HIDDEN;
    const int t = threadIdx.x;
    float4 v = ((const float4*)hr)[t];
    float s = v.x + v.y + v.z + v.w;
    float sq = v.x * v.x + v.y * v.y + v.z * v.z + v.w * v.w;
    __shared__ float rs[4], rq[4];
#pragma unroll
    for (int off = 32; off > 0; off >>= 1) {
        s += __shfl_down(s, off);
        sq += __shfl_down(sq, off);
    }
    if ((t & 63) == 0) { rs[t >> 6] = s; rq[t >> 6] = sq; }
    __syncthreads();
    s = rs[0] + rs[1] + rs[2] + rs[3];
    sq = rq[0] + rq[1] + rq[2] + rq[3];
    float mu = s * (1.0f / HIDDEN);
    float var = sq * (1.0f / HIDDEN) - mu * mu;
    float rinv = rsqrtf(var + LN_EPS);
    float4 g = ((const float4*)gamma)[t];
    float4 bt = ((const float4*)beta)[t];
    float4 o;
    o.x = (v.x - mu) * rinv * g.x + bt.x;
    o.y = (v.y - mu) * rinv * g.y + bt.y;
    o.z = (v.z - mu) * rinv * g.z + bt.z;
    o.w = (v.w - mu) * rinv * g.w + bt.w;
    ((float4*)(out + row * HIDDEN))[t] = o;
}

// ---------------- launch ----------------
extern "C" void kernel_launch(void* const* d_in, const int* in_sizes, int n_in,
                              void* d_out, int out_size, void* d_ws, size_t ws_size,
                              hipStream_t stream) {
    const float* x     = (const float*)d_in[0];
    const int*   mask  = (const int*)d_in[1];
    const float* Wq    = (const float*)d_in[2];
    const float* Wk    = (const float*)d_in[3];
    const float* Wv    = (const float*)d_in[4];
    const float* Wo    = (const float*)d_in[5];
    const float* bo    = (const float*)d_in[6];
    const float* gamma = (const float*)d_in[7];
    const float* beta  = (const float*)d_in[8];
    float* out = (float*)d_out;

    char* ws = (char*)d_ws;
    const long MB = 1024L * 1024L;
    bf16* yv   = (bf16*)(ws + 0 * MB);    // 32 MB (8192 x 2048) [y | VWc]
    float* h   = (float*)(ws + 0 * MB);   // 32 MB fp32, reuses yv after scores
    bf16* xb   = (bf16*)(ws + 32 * MB);   // 16 MB
    bf16* vt   = (bf16*)(ws + 48 * MB);   // 16 MB (per batch 1024 x 2048)
    bf16* wgc  = (bf16*)(ws + 64 * MB);   // 4 MB (2048 x 1024): [Gt ; Wc]
    bf16* wkT  = (bf16*)(ws + 68 * MB);   // 2 MB  -- A-block 0 (z=0)
    bf16* wo   = (bf16*)(ws + 70 * MB);   // 2 MB  -- A-block 1 (z=1)
    bf16* wqT  = (bf16*)(ws + 72 * MB);   // 2 MB  -- B-block 0
    bf16* wvT  = (bf16*)(ws + 74 * MB);   // 2 MB  -- B-block 1
    bf16* S    = (bf16*)(ws + 76 * MB);   // 32 MB scores/probs

    const int BS = BATCH * SEQ;  // 8192
    const int WW = HIDDEN * HIDDEN;
    dim3 blk256(256), blk512(512);

    // input + weight prep
    cvt_f32_bf16<<<dim3(BS * HIDDEN / 4 / 256), blk256, 0, stream>>>(x, xb, BS * HIDDEN / 4);
    cvt_f32_bf16<<<dim3(WW / 4 / 256), blk256, 0, stream>>>(Wo, wo, WW / 4);
    transpose_w3<<<dim3(16, 16, 3), blk256, 0, stream>>>(Wq, Wk, Wv, wqT, wkT, wvT);

    // [Gt ; Wc] in one z=2 launch (each z: 1024x1024, K=1024):
    //   z=0: Gt = wkT * wqT^T ; z=1: Wc = wo * wvT^T    grid 8x4x2
    gemm256<128, 0><<<dim3(HIDDEN / 128, HIDDEN / 256, 2), blk512, 0, stream>>>(
        wkT, wqT, wgc, nullptr, nullptr, HIDDEN, HIDDEN, HIDDEN, HIDDEN, 1.0f,
        (long)WW, (long)WW, (long)WW);

    // fused projection: yv = xb * wgc^T  (8192 x 2048)  [y = x*G | VWc]  grid 8x32 = 256
    gemm256<256, 0><<<dim3(2048 / 256, BS / 256, 1), blk512, 0, stream>>>(
        xb, wgc, yv, nullptr, nullptr, HIDDEN, HIDDEN, 2048, HIDDEN, 1.0f, 0, 0, 0);

    // VWc -> vt per batch
    transpose_v<<<dim3(HIDDEN / 64, SEQ / 64, BATCH), blk256, 0, stream>>>(yv, vt);

    // scores: per batch (2048x2048) = y * x^T * SCALE  grid 8x8x4 = 256
    gemm256<256, 0><<<dim3(SEQ / 256, SEQ / 256, BATCH), blk512, 0, stream>>>(
        yv, xb, S, nullptr, nullptr, 2048, HIDDEN, SEQ, HIDDEN, ATT_SCALE,
        (long)SEQ * 2048, (long)SEQ * HIDDEN, (long)SEQ * SEQ);

    softmax_rows<<<dim3(SEQ, BATCH), blk256, 0, stream>>>(S, mask);

    // h = P * vt^T + bo + x : per batch (2048x1024), K=2048, fp32 out  grid 8x8x4 = 256
    gemm256<128, 2><<<dim3(HIDDEN / 128, SEQ / 256, BATCH), blk512, 0, stream>>>(
        S, vt, h, bo, x, SEQ, SEQ, HIDDEN, SEQ, 1.0f,
        (long)SEQ * SEQ, (long)HIDDEN * SEQ, (long)SEQ * HIDDEN);

    layernorm_out<<<dim3(BS), blk256, 0, stream>>>(h, gamma, beta, out);
}